// Round 3
// baseline (31327.969 us; speedup 1.0000x reference)
//
#include <hip/hip_runtime.h>
#include <hip/hip_bf16.h>

typedef __hip_bfloat16 bf16;
typedef short bf8v __attribute__((ext_vector_type(8)));   // 8 x bf16 (4 VGPR)
typedef float f32x4 __attribute__((ext_vector_type(4)));

#define DEVINL __device__ __forceinline__
#define MFMA16(a, b, c) __builtin_amdgcn_mfma_f32_16x16x32_bf16((a), (b), (c), 0, 0, 0)

DEVINL float us2f(unsigned short u) { unsigned v = ((unsigned)u) << 16; return __uint_as_float(v); }
DEVINL float b2f(bf16 x) { return __bfloat162float(x); }
DEVINL bf16 f2b(float x) { return __float2bfloat16(x); }
DEVINL float sigf(float x) { return 1.0f / (1.0f + expf(-x)); }
DEVINL unsigned short f2bu(float f) { bf16 h = __float2bfloat16(f); return *(unsigned short*)&h; }

DEVINL void gload16(const void* g, void* l) {
  __builtin_amdgcn_global_load_lds((const __attribute__((address_space(1))) void*)g,
                                   (__attribute__((address_space(3))) void*)l, 16, 0, 0);
}

// ---------------- device-scope grid barrier ----------------
DEVINL void gridbar(unsigned* cnt, unsigned* gen, unsigned nblk) {
  __syncthreads();
  if (threadIdx.x == 0) {
    __threadfence();
    unsigned g = __hip_atomic_load(gen, __ATOMIC_RELAXED, __HIP_MEMORY_SCOPE_AGENT);
    unsigned t = __hip_atomic_fetch_add(cnt, 1u, __ATOMIC_ACQ_REL, __HIP_MEMORY_SCOPE_AGENT);
    if (t == nblk - 1) {
      __hip_atomic_store(cnt, 0u, __ATOMIC_RELAXED, __HIP_MEMORY_SCOPE_AGENT);
      __hip_atomic_fetch_add(gen, 1u, __ATOMIC_RELEASE, __HIP_MEMORY_SCOPE_AGENT);
    } else {
      while (__hip_atomic_load(gen, __ATOMIC_ACQUIRE, __HIP_MEMORY_SCOPE_AGENT) == g)
        __builtin_amdgcn_s_sleep(1);
    }
    __threadfence();
  }
  __syncthreads();
}

// ---------------- ws layout (bytes); total usage <= 272,629,760 (safe per round-1 run) ----
#define OKPT_H  ((size_t)0)
#define OKPT_L  ((size_t)8388608)
#define ORPT_H  ((size_t)16777216)
#define ORPT_L  ((size_t)25165824)
#define OWAT    ((size_t)33554432)
#define OXE_H   ((size_t)35651584)
#define OXE_L   ((size_t)69206016)
#define OHSF    ((size_t)35651584)     /* fp32 hs, aliases xe pair (dead post-GEMM) */
#define OHSB    ((size_t)102760448)    /* bf16 hs for score GEMM */
#define OSM     ((size_t)136314880)    /* small zone, zeroed, 2 MB */
#define OH0H    (OSM + 0)
#define OH0L    (OSM + 131072)
#define OH1H    (OSM + 262144)
#define OH1L    (OSM + 393216)
#define OCBUF   (OSM + 524288)
#define OBARS   (OSM + 786432)
#define OXK_L   ((size_t)138412032)    /* 134,217,728 -> ends 272,629,760 */
/* post-encoder aliases (dead regions) */
#define OWCT_H  ((size_t)0)
#define OWCT_L  ((size_t)4194304)
#define OPCTX   ((size_t)8388608)
#define OPSUM   ((size_t)12582912)
#define ORMAX   ((size_t)12584960)
#define ORIDX   ((size_t)12716032)
#define ORSUM   ((size_t)12847104)
#define OKRT_H  ((size_t)138412032)
#define OKRT_L  ((size_t)155189248)
#define OWOT_H  ((size_t)171966464)
#define OHSW    ((size_t)237502464)    /* ends 271,056,896 */

#define DELTA   1e-4f

// ---------------- utility kernels ----------------
__global__ void ed_zero_v3(float4* p, int n) {
  int i = blockIdx.x * 256 + threadIdx.x;
  if (i < n) p[i] = make_float4(0.f, 0.f, 0.f, 0.f);
}

__global__ void ed_transpose_v3(const float* __restrict__ in, bf16* __restrict__ out,
                                int R, int C, int ostride, int ooff, int perm) {
  __shared__ float tile[32][33];
  int c0 = blockIdx.x * 32, r0 = blockIdx.y * 32;
  int tx = threadIdx.x & 31, ty0 = threadIdx.x >> 5;
#pragma unroll
  for (int i = 0; i < 4; i++) {
    int ty = ty0 + i * 8;
    tile[ty][tx] = in[(size_t)(r0 + ty) * C + c0 + tx];
  }
  __syncthreads();
#pragma unroll
  for (int i = 0; i < 4; i++) {
    int ty = ty0 + i * 8;
    int c = c0 + ty;
    int oc = perm ? ((c & 1023) * 4 + (c >> 10)) : c;
    out[(size_t)oc * ostride + ooff + r0 + tx] = f2b(tile[tx][ty]);
  }
}

__global__ void ed_transpose_split_v3(const float* __restrict__ in, bf16* __restrict__ oh,
                                      bf16* __restrict__ ol, int R, int C, int ostride,
                                      int ooff, int perm) {
  __shared__ float tile[32][33];
  int c0 = blockIdx.x * 32, r0 = blockIdx.y * 32;
  int tx = threadIdx.x & 31, ty0 = threadIdx.x >> 5;
#pragma unroll
  for (int i = 0; i < 4; i++) {
    int ty = ty0 + i * 8;
    tile[ty][tx] = in[(size_t)(r0 + ty) * C + c0 + tx];
  }
  __syncthreads();
#pragma unroll
  for (int i = 0; i < 4; i++) {
    int ty = ty0 + i * 8;
    int c = c0 + ty;
    int oc = perm ? ((c & 1023) * 4 + (c >> 10)) : c;
    float v = tile[tx][ty];
    bf16 hh = f2b(v);
    size_t o = (size_t)oc * ostride + ooff + r0 + tx;
    oh[o] = hh;
    ol[o] = f2b(v - b2f(hh));
  }
}

__global__ void ed_gather_split_v3(const int* __restrict__ src, const float* __restrict__ emb,
                                   bf16* __restrict__ xh, bf16* __restrict__ xl) {
  int bid = blockIdx.x;
  int t = bid >> 6, b = bid & 63;
  int tok = src[b * 256 + t];
  const float* rowp = emb + (size_t)tok * 1024;
  int i = threadIdx.x * 4;
  float4 v = *(const float4*)(rowp + i);
  bf16 h0 = f2b(v.x), h1 = f2b(v.y), h2 = f2b(v.z), h3 = f2b(v.w);
  ushort4 oh, ol;
  oh.x = *(unsigned short*)&h0; oh.y = *(unsigned short*)&h1;
  oh.z = *(unsigned short*)&h2; oh.w = *(unsigned short*)&h3;
  ol.x = f2bu(v.x - b2f(h0)); ol.y = f2bu(v.y - b2f(h1));
  ol.z = f2bu(v.z - b2f(h2)); ol.w = f2bu(v.w - b2f(h3));
  *(ushort4*)(xh + (size_t)bid * 1024 + i) = oh;
  *(ushort4*)(xl + (size_t)bid * 1024 + i) = ol;
}

// ---------------- plain bf16 GEMM (hsW only; scores are precision-insensitive) ----------------
__global__ __launch_bounds__(256, 2) void ed_gemm_bt_v3(
    const bf16* __restrict__ A, const bf16* __restrict__ BT, bf16* __restrict__ C,
    int M, int N, int K) {
  __shared__ __align__(16) bf16 As[128 * 32];
  __shared__ __align__(16) bf16 Bs[128 * 32];
  int m0 = blockIdx.y * 128, n0 = blockIdx.x * 128;
  int tid = threadIdx.x, w = tid >> 6, l = tid & 63;
  int wm = w >> 1, wn = w & 1;
  int lr = l & 15, lq = l >> 4;
  f32x4 acc[4][4] = {};
  for (int k0 = 0; k0 < K; k0 += 32) {
    __syncthreads();
#pragma unroll
    for (int j = 0; j < 2; j++) {
      int o = (w * 2 + j) * 1024 + l * 16;
      int rrow = o >> 6, kk = (o & 63) >> 1;
      gload16(A + (size_t)(m0 + rrow) * K + k0 + kk, (char*)As + (w * 2 + j) * 1024);
      gload16(BT + (size_t)(n0 + rrow) * K + k0 + kk, (char*)Bs + (w * 2 + j) * 1024);
    }
    __syncthreads();
#pragma unroll
    for (int mi = 0; mi < 4; mi++) {
      bf8v a = *(const bf8v*)(As + (wm * 64 + mi * 16 + lr) * 32 + lq * 8);
#pragma unroll
      for (int ni = 0; ni < 4; ni++) {
        bf8v b = *(const bf8v*)(Bs + (wn * 64 + ni * 16 + lr) * 32 + lq * 8);
        acc[mi][ni] = MFMA16(a, b, acc[mi][ni]);
      }
    }
  }
#pragma unroll
  for (int mi = 0; mi < 4; mi++)
#pragma unroll
    for (int ni = 0; ni < 4; ni++)
#pragma unroll
      for (int r = 0; r < 4; r++)
        C[(size_t)(m0 + wm * 64 + mi * 16 + lq * 4 + r) * N + n0 + wn * 64 + ni * 16 + lr] =
            f2b(acc[mi][ni][r]);
}

// ---------------- split-precision GEMM (3-term), split output (Xk) ----------------
__global__ __launch_bounds__(256, 2) void ed_gemm3_v3(
    const bf16* __restrict__ Ah, const bf16* __restrict__ Al,
    const bf16* __restrict__ Bh, const bf16* __restrict__ Bl,
    bf16* __restrict__ Ch, bf16* __restrict__ Cl, int M, int N, int K) {
  __shared__ __align__(16) bf16 Ash[128 * 32];
  __shared__ __align__(16) bf16 Asl[128 * 32];
  __shared__ __align__(16) bf16 Bsh[128 * 32];
  __shared__ __align__(16) bf16 Bsl[128 * 32];
  int m0 = blockIdx.y * 128, n0 = blockIdx.x * 128;
  int tid = threadIdx.x, w = tid >> 6, l = tid & 63;
  int wm = w >> 1, wn = w & 1;
  int lr = l & 15, lq = l >> 4;
  f32x4 acc[4][4] = {};
  for (int k0 = 0; k0 < K; k0 += 32) {
    __syncthreads();
#pragma unroll
    for (int j = 0; j < 2; j++) {
      int o = (w * 2 + j) * 1024 + l * 16;
      int rrow = o >> 6, kk = (o & 63) >> 1;
      gload16(Ah + (size_t)(m0 + rrow) * K + k0 + kk, (char*)Ash + (w * 2 + j) * 1024);
      gload16(Al + (size_t)(m0 + rrow) * K + k0 + kk, (char*)Asl + (w * 2 + j) * 1024);
      gload16(Bh + (size_t)(n0 + rrow) * K + k0 + kk, (char*)Bsh + (w * 2 + j) * 1024);
      gload16(Bl + (size_t)(n0 + rrow) * K + k0 + kk, (char*)Bsl + (w * 2 + j) * 1024);
    }
    __syncthreads();
#pragma unroll
    for (int mi = 0; mi < 4; mi++) {
      bf8v a_h = *(const bf8v*)(Ash + (wm * 64 + mi * 16 + lr) * 32 + lq * 8);
      bf8v a_l = *(const bf8v*)(Asl + (wm * 64 + mi * 16 + lr) * 32 + lq * 8);
#pragma unroll
      for (int ni = 0; ni < 4; ni++) {
        bf8v b_h = *(const bf8v*)(Bsh + (wn * 64 + ni * 16 + lr) * 32 + lq * 8);
        bf8v b_l = *(const bf8v*)(Bsl + (wn * 64 + ni * 16 + lr) * 32 + lq * 8);
        acc[mi][ni] = MFMA16(a_h, b_h, acc[mi][ni]);
        acc[mi][ni] = MFMA16(a_h, b_l, acc[mi][ni]);
        acc[mi][ni] = MFMA16(a_l, b_h, acc[mi][ni]);
      }
    }
  }
#pragma unroll
  for (int mi = 0; mi < 4; mi++)
#pragma unroll
    for (int ni = 0; ni < 4; ni++)
#pragma unroll
      for (int r = 0; r < 4; r++) {
        float v = acc[mi][ni][r];
        bf16 hh = f2b(v);
        size_t idx = (size_t)(m0 + wm * 64 + mi * 16 + lq * 4 + r) * N + n0 + wn * 64 + ni * 16 + lr;
        Ch[idx] = hh;
        Cl[idx] = f2b(v - b2f(hh));
      }
}

// ---------------- encoder persistent kernel (4-term MFMA; fp32 hs out) ----------------
__global__ __launch_bounds__(256, 2) void ed_enc_v3(
    const int* __restrict__ src, const bf16* __restrict__ Rh, const bf16* __restrict__ Rl,
    const bf16* __restrict__ Xh, const bf16* __restrict__ Xl, const float* __restrict__ enc_b,
    bf16* h0h, bf16* h0l, bf16* h1h, bf16* h1l,
    float* __restrict__ cbuf, float* __restrict__ hsf, bf16* __restrict__ hsb, unsigned* bars) {
  int bid = blockIdx.x, tid = threadIdx.x;
  int bg = bid >> 6, cg = bid & 63;
  int w = tid >> 6, l = tid & 63, lr = l & 15, lq = l >> 4;
  int row = tid >> 4, ul = tid & 15;
  int b_ = bg * 16 + row, u = cg * 16 + ul;
  __shared__ float zl[16][68];
  float bi[4];
#pragma unroll
  for (int g = 0; g < 4; g++) {
    int colp = cg * 64 + ul * 4 + g;
    bi[g] = enc_b[(colp & 3) * 1024 + (colp >> 2)];
  }
  float c_ = 0.f;
  bf16 *hch = h0h, *hcl = h0l, *hnh = h1h, *hnl = h1l;
  const bf16* brh = Rh + (size_t)(cg * 64 + w * 16 + lr) * 1024;
  const bf16* brl = Rl + (size_t)(cg * 64 + w * 16 + lr) * 1024;
  for (int t = 0; t < 256; t++) {
    f32x4 acc = {0.f, 0.f, 0.f, 0.f};
    const bf16* arh = hch + (bg * 16 + lr) * 1024;
    const bf16* arl = hcl + (bg * 16 + lr) * 1024;
#pragma unroll 2
    for (int k0 = 0; k0 < 1024; k0 += 32) {
      bf8v a_h = *(const bf8v*)(arh + k0 + lq * 8);
      bf8v a_l = *(const bf8v*)(arl + k0 + lq * 8);
      bf8v b_h = *(const bf8v*)(brh + k0 + lq * 8);
      bf8v b_l = *(const bf8v*)(brl + k0 + lq * 8);
      acc = MFMA16(a_h, b_h, acc);
      acc = MFMA16(a_h, b_l, acc);
      acc = MFMA16(a_l, b_h, acc);
      acc = MFMA16(a_l, b_l, acc);
    }
#pragma unroll
    for (int r = 0; r < 4; r++) zl[lq * 4 + r][w * 16 + lr] = acc[r];
    __syncthreads();
    size_t xkb = ((size_t)t * 64 + b_) * 4096 + cg * 64 + ul * 4;
    ushort4 xh = *(const ushort4*)(Xh + xkb);
    ushort4 xlv = *(const ushort4*)(Xl + xkb);
    float zz0 = zl[row][ul * 4 + 0] + us2f(xh.x) + us2f(xlv.x) + bi[0];
    float zz1 = zl[row][ul * 4 + 1] + us2f(xh.y) + us2f(xlv.y) + bi[1];
    float zz2 = zl[row][ul * 4 + 2] + us2f(xh.z) + us2f(xlv.z) + bi[2];
    float zz3 = zl[row][ul * 4 + 3] + us2f(xh.w) + us2f(xlv.w) + bi[3];
    float iv = sigf(zz0), fv = sigf(zz1), gv = tanhf(zz2), ov = sigf(zz3);
    float cn = fv * c_ + iv * gv;
    float hnv = ov * tanhf(cn);
    bool m = src[b_ * 256 + t] > 0;
    float hold = b2f(hch[b_ * 1024 + u]) + b2f(hcl[b_ * 1024 + u]);
    float hv = m ? hnv : hold;
    c_ = m ? cn : c_;
    bf16 hh_ = f2b(hv);
    hnh[b_ * 1024 + u] = hh_;
    hnl[b_ * 1024 + u] = f2b(hv - b2f(hh_));
    hsf[((size_t)t * 64 + b_) * 1024 + u] = hv;
    hsb[((size_t)t * 64 + b_) * 1024 + u] = hh_;
    gridbar(bars + 0, bars + 1, 256);
    bf16* tp;
    tp = hch; hch = hnh; hnh = tp;
    tp = hcl; hcl = hnl; hnl = tp;
  }
  cbuf[b_ * 1024 + u] = c_;
}

// ---------------- decoder LSTM phase (4-term; x from fp32 emb) ----------------
DEVINL void dec_lstm_phase(int bg, int cg, int tid,
                           const bf16* __restrict__ hch, const bf16* __restrict__ hcl,
                           bf16* __restrict__ hnh, bf16* __restrict__ hnl,
                           const float* __restrict__ dec_emb,
                           const bf16* __restrict__ Kh, const bf16* __restrict__ Kl,
                           const float* __restrict__ dec_b, const int* yl,
                           float& c_, float (*zl)[68]) {
  int w = tid >> 6, l = tid & 63, lr = l & 15, lq = l >> 4;
  f32x4 acc = {0.f, 0.f, 0.f, 0.f};
  const bf16* brh = Kh + (size_t)(cg * 64 + w * 16 + lr) * 2048;
  const bf16* brl = Kl + (size_t)(cg * 64 + w * 16 + lr) * 2048;
  const float* xr = dec_emb + (size_t)yl[lr] * 1024 + lq * 8;
#pragma unroll 2
  for (int k0 = 0; k0 < 1024; k0 += 32) {
    float4 v0 = *(const float4*)(xr + k0);
    float4 v1 = *(const float4*)(xr + k0 + 4);
    float vs[8] = {v0.x, v0.y, v0.z, v0.w, v1.x, v1.y, v1.z, v1.w};
    bf8v a_h, a_l;
#pragma unroll
    for (int e = 0; e < 8; e++) {
      unsigned short uh = f2bu(vs[e]);
      a_h[e] = (short)uh;
      a_l[e] = (short)f2bu(vs[e] - us2f(uh));
    }
    bf8v b_h = *(const bf8v*)(brh + k0 + lq * 8);
    bf8v b_l = *(const bf8v*)(brl + k0 + lq * 8);
    acc = MFMA16(a_h, b_h, acc);
    acc = MFMA16(a_h, b_l, acc);
    acc = MFMA16(a_l, b_h, acc);
    acc = MFMA16(a_l, b_l, acc);
  }
  const bf16* hrh = hch + (bg * 16 + lr) * 1024;
  const bf16* hrl = hcl + (bg * 16 + lr) * 1024;
#pragma unroll 2
  for (int k0 = 0; k0 < 1024; k0 += 32) {
    bf8v a_h = *(const bf8v*)(hrh + k0 + lq * 8);
    bf8v a_l = *(const bf8v*)(hrl + k0 + lq * 8);
    bf8v b_h = *(const bf8v*)(brh + 1024 + k0 + lq * 8);
    bf8v b_l = *(const bf8v*)(brl + 1024 + k0 + lq * 8);
    acc = MFMA16(a_h, b_h, acc);
    acc = MFMA16(a_h, b_l, acc);
    acc = MFMA16(a_l, b_h, acc);
    acc = MFMA16(a_l, b_l, acc);
  }
#pragma unroll
  for (int r = 0; r < 4; r++) zl[lq * 4 + r][w * 16 + lr] = acc[r];
  __syncthreads();
  int row = tid >> 4, ul = tid & 15;
  int b_ = bg * 16 + row, u = cg * 16 + ul;
  float zz[4];
#pragma unroll
  for (int g = 0; g < 4; g++) {
    int colp = cg * 64 + ul * 4 + g;
    zz[g] = zl[row][ul * 4 + g] + dec_b[(colp & 3) * 1024 + (colp >> 2)];
  }
  float iv = sigf(zz[0]), fv = sigf(zz[1]), gv = tanhf(zz[2]), ov = sigf(zz[3]);
  float cn = fv * c_ + iv * gv;
  c_ = cn;
  float hv = ov * tanhf(cn);
  bf16 hh = f2b(hv);
  hnh[b_ * 1024 + u] = hh;
  hnl[b_ * 1024 + u] = f2b(hv - b2f(hh));
}

// ---------------- decoder persistent kernel ----------------
__global__ __launch_bounds__(256, 2) void ed_dec_v3(
    const int* __restrict__ src,
    const bf16* __restrict__ KRh, const bf16* __restrict__ KRl, const float* __restrict__ dec_b,
    const bf16* __restrict__ WcTh, const bf16* __restrict__ WcTl, const float* __restrict__ b_cp,
    const bf16* __restrict__ WoTh, const float* __restrict__ b_op,
    const float* __restrict__ Wout_f32, const float* __restrict__ dec_emb,
    const float* __restrict__ hsf, const bf16* __restrict__ hsW,
    bf16* h0h, bf16* h0l, bf16* h1h, bf16* h1l, float* __restrict__ cbuf,
    float* __restrict__ pctx, float* __restrict__ psum,
    bf16* __restrict__ ahh, bf16* __restrict__ ahl,
    float* __restrict__ rmax, int* __restrict__ ridx, float* __restrict__ rowsum,
    float* __restrict__ out, unsigned* bars) {
  int bid = blockIdx.x, tid = threadIdx.x;
  int bg = bid >> 6, cgl = bid & 63;  // LSTM / ah roles
  int ab = bid >> 2, akg = bid & 3;   // attention roles
  __shared__ float zl[16][68];
  __shared__ float e_lds[64 * 129];
  __shared__ float p3red[4][64][4];
  __shared__ float psc[64][5];
  __shared__ float ek[64];
  __shared__ float rowtot[64];
  __shared__ float inv_lds[16];
  __shared__ float gmx[16][17];
  __shared__ int ccnt[16];
  __shared__ int cand[16][8];
  __shared__ int y_lds[16];
  int row = tid >> 4, ul = tid & 15;
  float c_ = cbuf[(bg * 16 + row) * 1024 + cgl * 16 + ul];
  bf16 *hch = h0h, *hcl = h0l, *hnh = h1h, *hnl = h1l;
  unsigned *bc = bars + 2, *bgn = bars + 3;

  // PreP: LSTM with y0 = 1
  if (tid < 16) y_lds[tid] = 1;
  __syncthreads();
  dec_lstm_phase(bg, cgl, tid, hch, hcl, hnh, hnl, dec_emb, KRh, KRl, dec_b, y_lds, c_, zl);
  gridbar(bc, bgn, 256);
  {
    bf16* tp;
    tp = hch; hch = hnh; hnh = tp;
    tp = hcl; hcl = hnl; hnl = tp;
  }

  for (int st = 0; st < 32; st++) {
    // ---- P1: attention scores + exp + partial ctx (CU = (b, kg)) ----
    {
      int b_ = ab, kg = akg;
      int kl = tid >> 2, q = tid & 3;
      const bf16* hq = hch + b_ * 1024 + q * 256;
      const bf16* wrow = hsW + (((size_t)kg * 64 + kl) * 64 + b_) * 1024 + q * 256;
      float p = 0.f;
#pragma unroll 4
      for (int j = 0; j < 256; j += 8) {
        uint4 hv = *(const uint4*)(hq + j);
        uint4 wv = *(const uint4*)(wrow + j);
        p += us2f(hv.x & 0xffff) * us2f(wv.x & 0xffff) + us2f(hv.x >> 16) * us2f(wv.x >> 16);
        p += us2f(hv.y & 0xffff) * us2f(wv.y & 0xffff) + us2f(hv.y >> 16) * us2f(wv.y >> 16);
        p += us2f(hv.z & 0xffff) * us2f(wv.z & 0xffff) + us2f(hv.z >> 16) * us2f(wv.z >> 16);
        p += us2f(hv.w & 0xffff) * us2f(wv.w & 0xffff) + us2f(hv.w >> 16) * us2f(wv.w >> 16);
      }
      psc[kl][q] = p;
      __syncthreads();
      if (tid < 64) {
        float sc = psc[tid][0] + psc[tid][1] + psc[tid][2] + psc[tid][3];
        ek[tid] = (src[b_ * 256 + kg * 64 + tid] > 0) ? expf(sc) : 0.f;
      }
      __syncthreads();
      float a0 = 0.f, a1 = 0.f, a2 = 0.f, a3 = 0.f;
      for (int k2 = 0; k2 < 64; k2++) {
        float e = ek[k2];
        const float* hsrow = hsf + (((size_t)kg * 64 + k2) * 64 + b_) * 1024 + tid * 4;
        float4 uv = *(const float4*)hsrow;
        a0 += e * uv.x; a1 += e * uv.y; a2 += e * uv.z; a3 += e * uv.w;
      }
      *(float4*)(pctx + ((size_t)kg * 64 + b_) * 1024 + tid * 4) = make_float4(a0, a1, a2, a3);
      if (tid == 0) {
        float s_ = 0.f;
        for (int i = 0; i < 64; i++) s_ += ek[i];
        psum[kg * 64 + b_] = s_;
      }
    }
    gridbar(bc, bgn, 256);
    // ---- P3': in-block ctx reduce + ah = tanh(ctxh@W_c + b_c), 4-term ----
    {
      if (tid < 16) {
        int rb = bg * 16 + tid;
        float sg = psum[rb] + psum[64 + rb] + psum[128 + rb] + psum[192 + rb];
        inv_lds[tid] = 1.0f / sg;
      }
      __syncthreads();
      int w = tid >> 6, l = tid & 63, lr = l & 15, lq = l >> 4;
      int arow = bg * 16 + lr;
      float inv = inv_lds[lr];
      f32x4 acc = {0.f, 0.f, 0.f, 0.f};
      const bf16* bwh = WcTh + (size_t)(cgl * 16 + lr) * 2048;
      const bf16* bwl = WcTl + (size_t)(cgl * 16 + lr) * 2048;
      for (int k0 = w * 512; k0 < w * 512 + 512; k0 += 32) {
        int kk = k0 + lq * 8;
        bf8v a_h, a_l;
        if (k0 < 1024) {
          const float* pb = pctx + (size_t)arow * 1024 + kk;
          float4 q0a = *(const float4*)(pb);
          float4 q0b = *(const float4*)(pb + 4);
          float4 q1a = *(const float4*)(pb + 65536);
          float4 q1b = *(const float4*)(pb + 65540);
          float4 q2a = *(const float4*)(pb + 131072);
          float4 q2b = *(const float4*)(pb + 131076);
          float4 q3a = *(const float4*)(pb + 196608);
          float4 q3b = *(const float4*)(pb + 196612);
          float vs[8];
          vs[0] = (q0a.x + q1a.x + q2a.x + q3a.x) * inv;
          vs[1] = (q0a.y + q1a.y + q2a.y + q3a.y) * inv;
          vs[2] = (q0a.z + q1a.z + q2a.z + q3a.z) * inv;
          vs[3] = (q0a.w + q1a.w + q2a.w + q3a.w) * inv;
          vs[4] = (q0b.x + q1b.x + q2b.x + q3b.x) * inv;
          vs[5] = (q0b.y + q1b.y + q2b.y + q3b.y) * inv;
          vs[6] = (q0b.z + q1b.z + q2b.z + q3b.z) * inv;
          vs[7] = (q0b.w + q1b.w + q2b.w + q3b.w) * inv;
#pragma unroll
          for (int e = 0; e < 8; e++) {
            unsigned short uh = f2bu(vs[e]);
            a_h[e] = (short)uh;
            a_l[e] = (short)f2bu(vs[e] - us2f(uh));
          }
        } else {
          a_h = *(const bf8v*)(hch + arow * 1024 + kk - 1024);
          a_l = *(const bf8v*)(hcl + arow * 1024 + kk - 1024);
        }
        bf8v b_h = *(const bf8v*)(bwh + k0 + lq * 8);
        bf8v b_l = *(const bf8v*)(bwl + k0 + lq * 8);
        acc = MFMA16(a_h, b_h, acc);
        acc = MFMA16(a_h, b_l, acc);
        acc = MFMA16(a_l, b_h, acc);
        acc = MFMA16(a_l, b_l, acc);
      }
      *(f32x4*)&p3red[w][l][0] = acc;
      __syncthreads();
      if (w == 0) {
        int col = cgl * 16 + lr;
#pragma unroll
        for (int r = 0; r < 4; r++) {
          float v = p3red[0][l][r] + p3red[1][l][r] + p3red[2][l][r] + p3red[3][l][r] + b_cp[col];
          float ahv = tanhf(v);
          bf16 hh = f2b(ahv);
          ahh[(bg * 16 + lq * 4 + r) * 1024 + col] = hh;
          ahl[(bg * 16 + lq * 4 + r) * 1024 + col] = f2b(ahv - b2f(hh));
        }
      }
    }
    gridbar(bc, bgn, 256);
    // ---- P4: hi-only logits + per-CU exp-sum / top-2 ----
    {
      int w = tid >> 6, l = tid & 63, lr = l & 15, lq = l >> 4;
      int base = bid * 125;
      f32x4 acc[8] = {};
      const bf16* arh = ahh + (w * 16 + lr) * 1024;
#pragma unroll 2
      for (int k0 = 0; k0 < 1024; k0 += 32) {
        bf8v a_h = *(const bf8v*)(arh + k0 + lq * 8);
#pragma unroll
        for (int nt = 0; nt < 8; nt++) {
          int cl = nt * 16 + lr;
          int cc = cl < 125 ? cl : 124;
          bf8v b_h = *(const bf8v*)(WoTh + (size_t)(base + cc) * 1024 + k0 + lq * 8);
          acc[nt] = MFMA16(a_h, b_h, acc[nt]);
        }
      }
#pragma unroll
      for (int nt = 0; nt < 8; nt++) {
        int cl = nt * 16 + lr;
        if (cl < 125) {
#pragma unroll
          for (int r = 0; r < 4; r++) {
            int rr = w * 16 + lq * 4 + r;
            e_lds[rr * 129 + cl] = acc[nt][r] + b_op[base + cl];
          }
        }
      }
      __syncthreads();
      if (tid < 64) {
        float sm = 0.f, v1 = -1e30f, v2 = -1e30f;
        int i1 = 0, i2 = 0;
        for (int c2 = 0; c2 < 125; c2++) {
          float v = e_lds[tid * 129 + c2];
          sm += expf(v);
          if (v > v1) { v2 = v1; i2 = i1; v1 = v; i1 = base + c2; }
          else if (v > v2) { v2 = v; i2 = base + c2; }
        }
        rowsum[bid * 64 + tid] = sm;
        rmax[(bid * 64 + tid) * 2 + 0] = v1;
        ridx[(bid * 64 + tid) * 2 + 0] = i1;
        rmax[(bid * 64 + tid) * 2 + 1] = v2;
        ridx[(bid * 64 + tid) * 2 + 1] = i2;
      }
    }
    gridbar(bc, bgn, 256);
    // ---- P5: probs write + candidate refine (f64) + next LSTM ----
    {
      int rr = tid & 63, pp = tid >> 6;
      float s_ = 0.f;
      for (int cu2 = pp * 64; cu2 < pp * 64 + 64; cu2++) s_ += rowsum[cu2 * 64 + rr];
      psc[rr][pp] = s_;
      __syncthreads();
      if (tid < 64) rowtot[tid] = psc[tid][0] + psc[tid][1] + psc[tid][2] + psc[tid][3];
      __syncthreads();
      int base = bid * 125;
      for (int i = tid; i < 8000; i += 256) {
        int r_ = i / 125, c2 = i - r_ * 125;
        out[((size_t)r_ * 32 + st) * 32000 + base + c2] = expf(e_lds[r_ * 129 + c2]) / rowtot[r_];
      }
      if (st < 31) {
        // candidate discovery: parallel max + collect
        {
          int r16 = tid & 15, ch = tid >> 4;
          int rowg = bg * 16 + r16;
          float m_ = -1e30f;
          for (int e = ch * 32; e < ch * 32 + 32; e++)
            m_ = fmaxf(m_, rmax[((e >> 1) * 64 + rowg) * 2 + (e & 1)]);
          gmx[r16][ch] = m_;
        }
        if (tid < 16) ccnt[tid] = 0;
        __syncthreads();
        {
          int r16 = tid & 15, ch = tid >> 4;
          int rowg = bg * 16 + r16;
          float gm_ = gmx[r16][0];
#pragma unroll
          for (int j = 1; j < 16; j++) gm_ = fmaxf(gm_, gmx[r16][j]);
          for (int e = ch * 32; e < ch * 32 + 32; e++) {
            float v = rmax[((e >> 1) * 64 + rowg) * 2 + (e & 1)];
            if (v >= gm_ - DELTA) {
              int slot = atomicAdd(&ccnt[r16], 1);
              if (slot < 8) cand[r16][slot] = ridx[((e >> 1) * 64 + rowg) * 2 + (e & 1)];
            }
          }
        }
        __syncthreads();
        // f64 refine: wave w handles rows w, w+4, w+8, w+12
        {
          int w = tid >> 6, l = tid & 63;
          for (int p = 0; p < 4; p++) {
            int r16 = p * 4 + w;
            int rowg = bg * 16 + r16;
            int cnt = ccnt[r16] < 8 ? ccnt[r16] : 8;
            double bv = -1e30;
            int bi = 0x7fffffff;
            for (int ci = 0; ci < cnt; ci++) {
              int c = cand[r16][ci];
              double s = 0.0;
              for (int k = l; k < 1024; k += 64) {
                float av = b2f(ahh[rowg * 1024 + k]) + b2f(ahl[rowg * 1024 + k]);
                s += (double)av * (double)Wout_f32[(size_t)k * 32000 + c];
              }
#pragma unroll
              for (int off = 32; off > 0; off >>= 1) s += __shfl_down(s, off);
              if (l == 0) {
                s += (double)b_op[c];
                if (s > bv || (s == bv && c < bi)) { bv = s; bi = c; }
              }
            }
            if (l == 0) y_lds[r16] = bi;
          }
        }
        __syncthreads();
        dec_lstm_phase(bg, cgl, tid, hch, hcl, hnh, hnl, dec_emb, KRh, KRl, dec_b, y_lds, c_, zl);
      }
    }
    gridbar(bc, bgn, 256);
    {
      bf16* tp;
      tp = hch; hch = hnh; hnh = tp;
      tp = hcl; hcl = hnl; hnl = tp;
    }
  }
}

// ---------------- host launch ----------------
extern "C" void kernel_launch(void* const* d_in, const int* in_sizes, int n_in,
                              void* d_out, int out_size, void* d_ws, size_t ws_size,
                              hipStream_t stream) {
  (void)in_sizes; (void)n_in; (void)out_size; (void)ws_size;
  const int*   src     = (const int*)  d_in[0];
  const float* enc_emb = (const float*)d_in[1];
  const float* enc_K   = (const float*)d_in[2];
  const float* enc_R   = (const float*)d_in[3];
  const float* enc_b   = (const float*)d_in[4];
  const float* dec_emb = (const float*)d_in[5];
  const float* dec_K   = (const float*)d_in[6];
  const float* dec_R   = (const float*)d_in[7];
  const float* dec_b   = (const float*)d_in[8];
  const float* W_a     = (const float*)d_in[9];
  const float* W_c     = (const float*)d_in[10];
  const float* b_c     = (const float*)d_in[11];
  const float* W_out   = (const float*)d_in[12];
  const float* b_out   = (const float*)d_in[13];
  char* ws = (char*)d_ws;

  bf16* KpTh = (bf16*)(ws + OKPT_H);
  bf16* KpTl = (bf16*)(ws + OKPT_L);
  bf16* RpTh = (bf16*)(ws + ORPT_H);
  bf16* RpTl = (bf16*)(ws + ORPT_L);
  bf16* WaT  = (bf16*)(ws + OWAT);
  bf16* xeh  = (bf16*)(ws + OXE_H);
  bf16* xel  = (bf16*)(ws + OXE_L);
  float* hsf = (float*)(ws + OHSF);
  bf16* hsb  = (bf16*)(ws + OHSB);
  bf16* h0h  = (bf16*)(ws + OH0H);
  bf16* h0l  = (bf16*)(ws + OH0L);
  bf16* h1h  = (bf16*)(ws + OH1H);
  bf16* h1l  = (bf16*)(ws + OH1L);
  float* cbuf = (float*)(ws + OCBUF);
  unsigned* bars = (unsigned*)(ws + OBARS);
  bf16* XkL  = (bf16*)(ws + OXK_L);
  bf16* XkH  = (bf16*)d_out;  // consumed by encoder before decoder writes probs
  bf16* WcTh = (bf16*)(ws + OWCT_H);
  bf16* WcTl = (bf16*)(ws + OWCT_L);
  float* pctx = (float*)(ws + OPCTX);
  float* psum = (float*)(ws + OPSUM);
  float* rmaxp = (float*)(ws + ORMAX);
  int*  ridxp = (int*)(ws + ORIDX);
  float* rsum = (float*)(ws + ORSUM);
  bf16* KRTh = (bf16*)(ws + OKRT_H);
  bf16* KRTl = (bf16*)(ws + OKRT_L);
  bf16* WoTh = (bf16*)(ws + OWOT_H);
  bf16* hsW  = (bf16*)(ws + OHSW);
  // ah pair: reuse WcT-adjacent scratch (dead KpT region beyond WcT): place after rsum
  bf16* ahh  = (bf16*)(ws + ORSUM + 65536);            // 64*1024*2 = 131072
  bf16* ahl  = (bf16*)(ws + ORSUM + 65536 + 131072);   // ends < 13.2 MB, inside dead KpT

  // zero small state (h pairs, cbuf, barriers)
  ed_zero_v3<<<512, 256, 0, stream>>>((float4*)(ws + OSM), 131072);
  // stage-A weight prep
  ed_transpose_split_v3<<<dim3(128, 32), 256, 0, stream>>>(enc_K, KpTh, KpTl, 1024, 4096, 1024, 0, 1);
  ed_transpose_split_v3<<<dim3(128, 32), 256, 0, stream>>>(enc_R, RpTh, RpTl, 1024, 4096, 1024, 0, 1);
  ed_transpose_v3<<<dim3(32, 32), 256, 0, stream>>>(W_a, WaT, 1024, 1024, 1024, 0, 0);
  ed_gather_split_v3<<<16384, 256, 0, stream>>>(src, enc_emb, xeh, xel);
  // Xk = xe @ enc_K (split), hi -> d_out, lo -> ws
  ed_gemm3_v3<<<dim3(32, 128), 256, 0, stream>>>(xeh, xel, KpTh, KpTl, XkH, XkL, 16384, 4096, 1024);
  // encoder recurrence (writes fp32 hs over dead xe region)
  ed_enc_v3<<<256, 256, 0, stream>>>(src, RpTh, RpTl, XkH, XkL, enc_b, h0h, h0l, h1h, h1l,
                                     cbuf, hsf, hsb, bars);
  // hsW = hs @ W_a (plain bf16)
  ed_gemm_bt_v3<<<dim3(8, 128), 256, 0, stream>>>(hsb, WaT, hsW, 16384, 1024, 1024);
  // decoder weight prep (into dead regions)
  ed_transpose_split_v3<<<dim3(128, 32), 256, 0, stream>>>(dec_K, KRTh, KRTl, 1024, 4096, 2048, 0, 1);
  ed_transpose_split_v3<<<dim3(128, 32), 256, 0, stream>>>(dec_R, KRTh, KRTl, 1024, 4096, 2048, 1024, 1);
  ed_transpose_split_v3<<<dim3(32, 64), 256, 0, stream>>>(W_c, WcTh, WcTl, 2048, 1024, 2048, 0, 0);
  ed_transpose_v3<<<dim3(1000, 32), 256, 0, stream>>>(W_out, WoTh, 1024, 32000, 1024, 0, 0);
  // decoder
  ed_dec_v3<<<256, 256, 0, stream>>>(src, KRTh, KRTl, dec_b, WcTh, WcTl, b_c, WoTh, b_out,
                                     W_out, dec_emb, hsf, hsW, h0h, h0l, h1h, h1l, cbuf,
                                     pctx, psum, ahh, ahl, rmaxp, ridxp, rsum,
                                     (float*)d_out, bars);
}

// Round 5
// 15108.929 us; speedup vs baseline: 2.0735x; 2.0735x over previous
//
#include <hip/hip_runtime.h>
#include <hip/hip_bf16.h>

typedef __hip_bfloat16 bf16;
typedef short bf8v __attribute__((ext_vector_type(8)));   // 8 x bf16 (4 VGPR)
typedef float f32x4 __attribute__((ext_vector_type(4)));

#define DEVINL __device__ __forceinline__
#define MFMA16(a, b, c) __builtin_amdgcn_mfma_f32_16x16x32_bf16((a), (b), (c), 0, 0, 0)

DEVINL float us2f(unsigned short u) { unsigned v = ((unsigned)u) << 16; return __uint_as_float(v); }
DEVINL float b2f(bf16 x) { return __bfloat162float(x); }
DEVINL bf16 f2b(float x) { return __float2bfloat16(x); }
DEVINL float sigf(float x) { return 1.0f / (1.0f + expf(-x)); }
DEVINL unsigned short f2bu(float f) { bf16 h = __float2bfloat16(f); return *(unsigned short*)&h; }

DEVINL void gload16(const void* g, void* l) {
  __builtin_amdgcn_global_load_lds((const __attribute__((address_space(1))) void*)g,
                                   (__attribute__((address_space(3))) void*)l, 16, 0, 0);
}

// ---- relaxed agent-scope atomics: coherence-point access, no L2 flush/inv ----
DEVINL unsigned ald(const unsigned* p) {
  return __hip_atomic_load(p, __ATOMIC_RELAXED, __HIP_MEMORY_SCOPE_AGENT);
}
DEVINL void ast(unsigned* p, unsigned v) {
  __hip_atomic_store(p, v, __ATOMIC_RELAXED, __HIP_MEMORY_SCOPE_AGENT);
}
DEVINL float aldf(const float* p) { unsigned u = ald((const unsigned*)p); return __uint_as_float(u); }
DEVINL void astf(float* p, float v) { ast((unsigned*)p, __float_as_uint(v)); }

// ---- two-level grid barrier (8 groups x 32), relaxed ops, parity-buffered ----
DEVINL void gridbar2(unsigned* bars, unsigned lgen) {
  __syncthreads();  // drains vmcnt before s_barrier -> prior stores complete
  if (threadIdx.x == 0) {
    unsigned s = lgen & 1;
    unsigned g = blockIdx.x >> 5;
    unsigned* grp = bars + (g * 2 + s) * 16;
    unsigned* top = bars + (16 + s) * 16;
    unsigned* gen = bars + 288;
    unsigned t = __hip_atomic_fetch_add(grp, 1u, __ATOMIC_RELAXED, __HIP_MEMORY_SCOPE_AGENT);
    if (t == 31u) {
      ast(grp, 0u);
      unsigned tt = __hip_atomic_fetch_add(top, 1u, __ATOMIC_RELAXED, __HIP_MEMORY_SCOPE_AGENT);
      if (tt == 7u) {
        ast(top, 0u);
        asm volatile("s_waitcnt vmcnt(0)");
        ast(gen, lgen + 1u);
      }
    }
    while (ald(gen) <= lgen) __builtin_amdgcn_s_sleep(4);
  }
  __syncthreads();
}

// ---------------- ws layout (bytes); total <= 272,629,760 (proven-safe budget) ----
#define OKPT_H  ((size_t)0)
#define OKPT_L  ((size_t)8388608)
#define ORPT_H  ((size_t)16777216)
#define ORPT_L  ((size_t)25165824)
#define OWAT    ((size_t)33554432)
#define OXE_H   ((size_t)35651584)
#define OXE_L   ((size_t)69206016)
#define OHSF5   ((size_t)35651584)    /* fp32 hs (67,108,864) over dead xe pair */
#define OHSB5   ((size_t)102760448)   /* bf16 hs for hsW GEMM */
#define XCH     ((size_t)136314880)   /* 2 MiB exchange zone, zeroed each launch */
#define OHPK_E0 (XCH + 0)
#define OHPK_E1 (XCH + 262144)
#define OHPK_D0 (XCH + 524288)
#define OCBUF5  (XCH + 1048576)
#define OAHPK   (XCH + 1310720)
#define ORSUM5  (XCH + 1572864)
#define ORMAX5  (XCH + 1638400)
#define ORIDX5  (XCH + 1769472)
#define OPSUM5  (XCH + 1900544)
#define OBARS5  (XCH + 1901568)
#define OXK_L5  ((size_t)138412032)   /* 134,217,728 -> ends 272,629,760 */
/* post-encoder aliases over dead regions */
#define OWCT_H  ((size_t)0)
#define OWCT_L  ((size_t)4194304)
#define OPCTX5  ((size_t)8388608)
#define OWOT5   ((size_t)138412032)   /* 65,536,000 -> 203,948,032 */
#define OKRTH5  ((size_t)203948032)   /* 16,777,216 -> 220,725,248 */
#define OKRTL5  ((size_t)220725248)   /* -> 237,502,464 */
#define OHSW5   ((size_t)237502464)   /* 33,554,432 -> 271,056,896 */

#define DELTA   1e-4f

// decoder LDS pool offsets (pool size 131,456)
#define D_LH   0
#define D_LL   32768
#define D_ZS   65536
#define D_AST  0
#define D_E    0
#define D_HBF  0
#define D_PSC  4096
#define D_EK   8448
#define D_PC4  8704
#define D_ZS3  0
#define D_PSC2 33024
#define D_GMX  37376
#define D_CCN  41536
#define D_CAND 41600
#define D_YL   131072
#define D_INV  131136
#define D_RT   131200

// ---------------- utility kernels ----------------
__global__ void ed_zero_v5(float4* p, int n) {
  int i = blockIdx.x * 256 + threadIdx.x;
  if (i < n) p[i] = make_float4(0.f, 0.f, 0.f, 0.f);
}

__global__ void ed_transpose_v5(const float* __restrict__ in, bf16* __restrict__ out,
                                int R, int C, int ostride, int ooff, int perm) {
  __shared__ float tile[32][33];
  int c0 = blockIdx.x * 32, r0 = blockIdx.y * 32;
  int tx = threadIdx.x & 31, ty0 = threadIdx.x >> 5;
#pragma unroll
  for (int i = 0; i < 4; i++) {
    int ty = ty0 + i * 8;
    tile[ty][tx] = in[(size_t)(r0 + ty) * C + c0 + tx];
  }
  __syncthreads();
#pragma unroll
  for (int i = 0; i < 4; i++) {
    int ty = ty0 + i * 8;
    int c = c0 + ty;
    int oc = perm ? ((c & 1023) * 4 + (c >> 10)) : c;
    out[(size_t)oc * ostride + ooff + r0 + tx] = f2b(tile[tx][ty]);
  }
}

__global__ void ed_transpose_split_v5(const float* __restrict__ in, bf16* __restrict__ oh,
                                      bf16* __restrict__ ol, int R, int C, int ostride,
                                      int ooff, int perm) {
  __shared__ float tile[32][33];
  int c0 = blockIdx.x * 32, r0 = blockIdx.y * 32;
  int tx = threadIdx.x & 31, ty0 = threadIdx.x >> 5;
#pragma unroll
  for (int i = 0; i < 4; i++) {
    int ty = ty0 + i * 8;
    tile[ty][tx] = in[(size_t)(r0 + ty) * C + c0 + tx];
  }
  __syncthreads();
#pragma unroll
  for (int i = 0; i < 4; i++) {
    int ty = ty0 + i * 8;
    int c = c0 + ty;
    int oc = perm ? ((c & 1023) * 4 + (c >> 10)) : c;
    float v = tile[tx][ty];
    bf16 hh = f2b(v);
    size_t o = (size_t)oc * ostride + ooff + r0 + tx;
    oh[o] = hh;
    ol[o] = f2b(v - b2f(hh));
  }
}

__global__ void ed_gather_split_v5(const int* __restrict__ src, const float* __restrict__ emb,
                                   bf16* __restrict__ xh, bf16* __restrict__ xl) {
  int bid = blockIdx.x;
  int t = bid >> 6, b = bid & 63;
  int tok = src[b * 256 + t];
  const float* rowp = emb + (size_t)tok * 1024;
  int i = threadIdx.x * 4;
  float4 v = *(const float4*)(rowp + i);
  bf16 h0 = f2b(v.x), h1 = f2b(v.y), h2 = f2b(v.z), h3 = f2b(v.w);
  ushort4 oh, ol;
  oh.x = *(unsigned short*)&h0; oh.y = *(unsigned short*)&h1;
  oh.z = *(unsigned short*)&h2; oh.w = *(unsigned short*)&h3;
  ol.x = f2bu(v.x - b2f(h0)); ol.y = f2bu(v.y - b2f(h1));
  ol.z = f2bu(v.z - b2f(h2)); ol.w = f2bu(v.w - b2f(h3));
  *(ushort4*)(xh + (size_t)bid * 1024 + i) = oh;
  *(ushort4*)(xl + (size_t)bid * 1024 + i) = ol;
}

// ---------------- plain bf16 GEMM (hsW only) ----------------
__global__ __launch_bounds__(256, 2) void ed_gemm_bt_v5(
    const bf16* __restrict__ A, const bf16* __restrict__ BT, bf16* __restrict__ C,
    int M, int N, int K) {
  __shared__ __align__(16) bf16 As[128 * 32];
  __shared__ __align__(16) bf16 Bs[128 * 32];
  int m0 = blockIdx.y * 128, n0 = blockIdx.x * 128;
  int tid = threadIdx.x, w = tid >> 6, l = tid & 63;
  int wm = w >> 1, wn = w & 1;
  int lr = l & 15, lq = l >> 4;
  f32x4 acc[4][4] = {};
  for (int k0 = 0; k0 < K; k0 += 32) {
    __syncthreads();
#pragma unroll
    for (int j = 0; j < 2; j++) {
      int o = (w * 2 + j) * 1024 + l * 16;
      int rrow = o >> 6, kk = (o & 63) >> 1;
      gload16(A + (size_t)(m0 + rrow) * K + k0 + kk, (char*)As + (w * 2 + j) * 1024);
      gload16(BT + (size_t)(n0 + rrow) * K + k0 + kk, (char*)Bs + (w * 2 + j) * 1024);
    }
    __syncthreads();
#pragma unroll
    for (int mi = 0; mi < 4; mi++) {
      bf8v a = *(const bf8v*)(As + (wm * 64 + mi * 16 + lr) * 32 + lq * 8);
#pragma unroll
      for (int ni = 0; ni < 4; ni++) {
        bf8v b = *(const bf8v*)(Bs + (wn * 64 + ni * 16 + lr) * 32 + lq * 8);
        acc[mi][ni] = MFMA16(a, b, acc[mi][ni]);
      }
    }
  }
#pragma unroll
  for (int mi = 0; mi < 4; mi++)
#pragma unroll
    for (int ni = 0; ni < 4; ni++)
#pragma unroll
      for (int r = 0; r < 4; r++)
        C[(size_t)(m0 + wm * 64 + mi * 16 + lq * 4 + r) * N + n0 + wn * 64 + ni * 16 + lr] =
            f2b(acc[mi][ni][r]);
}

// ---------------- split-precision GEMM (3-term), split output (Xk) ----------------
__global__ __launch_bounds__(256, 2) void ed_gemm3_v5(
    const bf16* __restrict__ Ah, const bf16* __restrict__ Al,
    const bf16* __restrict__ Bh, const bf16* __restrict__ Bl,
    bf16* __restrict__ Ch, bf16* __restrict__ Cl, int M, int N, int K) {
  __shared__ __align__(16) bf16 Ash[128 * 32];
  __shared__ __align__(16) bf16 Asl[128 * 32];
  __shared__ __align__(16) bf16 Bsh[128 * 32];
  __shared__ __align__(16) bf16 Bsl[128 * 32];
  int m0 = blockIdx.y * 128, n0 = blockIdx.x * 128;
  int tid = threadIdx.x, w = tid >> 6, l = tid & 63;
  int wm = w >> 1, wn = w & 1;
  int lr = l & 15, lq = l >> 4;
  f32x4 acc[4][4] = {};
  for (int k0 = 0; k0 < K; k0 += 32) {
    __syncthreads();
#pragma unroll
    for (int j = 0; j < 2; j++) {
      int o = (w * 2 + j) * 1024 + l * 16;
      int rrow = o >> 6, kk = (o & 63) >> 1;
      gload16(Ah + (size_t)(m0 + rrow) * K + k0 + kk, (char*)Ash + (w * 2 + j) * 1024);
      gload16(Al + (size_t)(m0 + rrow) * K + k0 + kk, (char*)Asl + (w * 2 + j) * 1024);
      gload16(Bh + (size_t)(n0 + rrow) * K + k0 + kk, (char*)Bsh + (w * 2 + j) * 1024);
      gload16(Bl + (size_t)(n0 + rrow) * K + k0 + kk, (char*)Bsl + (w * 2 + j) * 1024);
    }
    __syncthreads();
#pragma unroll
    for (int mi = 0; mi < 4; mi++) {
      bf8v a_h = *(const bf8v*)(Ash + (wm * 64 + mi * 16 + lr) * 32 + lq * 8);
      bf8v a_l = *(const bf8v*)(Asl + (wm * 64 + mi * 16 + lr) * 32 + lq * 8);
#pragma unroll
      for (int ni = 0; ni < 4; ni++) {
        bf8v b_h = *(const bf8v*)(Bsh + (wn * 64 + ni * 16 + lr) * 32 + lq * 8);
        bf8v b_l = *(const bf8v*)(Bsl + (wn * 64 + ni * 16 + lr) * 32 + lq * 8);
        acc[mi][ni] = MFMA16(a_h, b_h, acc[mi][ni]);
        acc[mi][ni] = MFMA16(a_h, b_l, acc[mi][ni]);
        acc[mi][ni] = MFMA16(a_l, b_h, acc[mi][ni]);
      }
    }
  }
#pragma unroll
  for (int mi = 0; mi < 4; mi++)
#pragma unroll
    for (int ni = 0; ni < 4; ni++)
#pragma unroll
      for (int r = 0; r < 4; r++) {
        float v = acc[mi][ni][r];
        bf16 hh = f2b(v);
        size_t idx = (size_t)(m0 + wm * 64 + mi * 16 + lq * 4 + r) * N + n0 + wn * 64 + ni * 16 + lr;
        Ch[idx] = hh;
        Cl[idx] = f2b(v - b2f(hh));
      }
}

// ---------------- encoder: 1024 thr, R in VGPRs, atomic h-exchange ----------------
__global__ __launch_bounds__(1024, 4) void ed_enc_v5(
    const int* __restrict__ src, const bf16* __restrict__ Rh, const bf16* __restrict__ Rl,
    const bf16* __restrict__ Xh, const bf16* __restrict__ Xl, const float* __restrict__ enc_b,
    unsigned* hpk0, unsigned* hpk1, float* __restrict__ cbuf,
    float* __restrict__ hsf, bf16* __restrict__ hsb, unsigned* bars) {
  extern __shared__ char sm[];
  bf16* lh = (bf16*)sm;                 // [16][1024] swizzled
  bf16* ll = (bf16*)(sm + 32768);
  float* zs = (float*)(sm + 65536);     // [64][68]
  float* xkf = (float*)(sm + 82944);    // [16][64]
  int bid = blockIdx.x, tid = threadIdx.x;
  int bg = bid >> 6, cg = bid & 63;
  int wv = tid >> 6, l = tid & 63, lr = l & 15, lq = l >> 4;
  int kq = wv >> 2, cs = wv & 3;
  int srow = tid >> 6, sj0 = (tid & 63) * 16;
  int grow = tid >> 4, gul = tid & 15;
  bf8v Rh_[8], Rl_[8];
  {
    const bf16* bh = Rh + (size_t)(cg * 64 + cs * 16 + lr) * 1024 + kq * 256 + lq * 8;
    const bf16* bl = Rl + (size_t)(cg * 64 + cs * 16 + lr) * 1024 + kq * 256 + lq * 8;
#pragma unroll
    for (int i = 0; i < 8; i++) {
      Rh_[i] = *(const bf8v*)(bh + i * 32);
      Rl_[i] = *(const bf8v*)(bl + i * 32);
    }
  }
  float bi[4];
  float c_ = 0.f;
  if (tid < 256) {
#pragma unroll
    for (int g = 0; g < 4; g++) {
      int colp = cg * 64 + gul * 4 + g;
      bi[g] = enc_b[(colp & 3) * 1024 + (colp >> 2)];
    }
  }
  unsigned *hc = hpk0, *hn = hpk1;
  unsigned lgen = 0;
  for (int t = 0; t < 256; t++) {
    {
      const unsigned* hrow = hc + (size_t)(bg * 16 + srow) * 1024 + sj0;
      unsigned u[16];
#pragma unroll
      for (int j = 0; j < 16; j++) u[j] = ald(hrow + j);
      int r8 = (srow & 7) << 3;
#pragma unroll
      for (int j = 0; j < 16; j += 2) {
        int es = (sj0 + j) ^ r8;
        *(unsigned*)((char*)lh + srow * 2048 + es * 2) = (u[j] >> 16) | (u[j + 1] & 0xffff0000u);
        *(unsigned*)((char*)ll + srow * 2048 + es * 2) = (u[j] & 0xffffu) | (u[j + 1] << 16);
      }
    }
    {
      int xr = tid >> 6, xc = tid & 63;
      size_t xi = ((size_t)t * 64 + bg * 16 + xr) * 4096 + cg * 64 + xc;
      xkf[xr * 64 + xc] = us2f(*(const unsigned short*)(Xh + xi)) +
                          us2f(*(const unsigned short*)(Xl + xi));
    }
    __syncthreads();
    {
      f32x4 acc = {0.f, 0.f, 0.f, 0.f};
      int r8 = (lr & 7) << 3;
#pragma unroll
      for (int i = 0; i < 8; i++) {
        int e0 = kq * 256 + i * 32 + lq * 8;
        int es = e0 ^ r8;
        bf8v a_h = *(const bf8v*)((char*)lh + lr * 2048 + es * 2);
        bf8v a_l = *(const bf8v*)((char*)ll + lr * 2048 + es * 2);
        acc = MFMA16(a_h, Rh_[i], acc);
        acc = MFMA16(a_h, Rl_[i], acc);
        acc = MFMA16(a_l, Rh_[i], acc);
        acc = MFMA16(a_l, Rl_[i], acc);
      }
#pragma unroll
      for (int r = 0; r < 4; r++) zs[(kq * 16 + lq * 4 + r) * 68 + cs * 16 + lr] = acc[r];
    }
    __syncthreads();
    if (tid < 256) {
      int b_ = bg * 16 + grow, u = cg * 16 + gul;
      float zz[4];
#pragma unroll
      for (int g = 0; g < 4; g++) {
        int cc = gul * 4 + g;
        zz[g] = zs[(0 + grow) * 68 + cc] + zs[(16 + grow) * 68 + cc] +
                zs[(32 + grow) * 68 + cc] + zs[(48 + grow) * 68 + cc] +
                xkf[grow * 64 + cc] + bi[g];
      }
      float iv = sigf(zz[0]), fv = sigf(zz[1]), gv = tanhf(zz[2]), ov = sigf(zz[3]);
      float cn = fv * c_ + iv * gv;
      float hnv = ov * tanhf(cn);
      bool m = src[b_ * 256 + t] > 0;
      int es = u ^ ((grow & 7) << 3);
      float hold = b2f(*(const bf16*)((char*)lh + grow * 2048 + es * 2)) +
                   b2f(*(const bf16*)((char*)ll + grow * 2048 + es * 2));
      float hv = m ? hnv : hold;
      c_ = m ? cn : c_;
      unsigned short uh = f2bu(hv);
      unsigned pkv = ((unsigned)uh << 16) | (unsigned)f2bu(hv - us2f(uh));
      ast(hn + (size_t)b_ * 1024 + u, pkv);
      hsf[((size_t)t * 64 + b_) * 1024 + u] = hv;
      hsb[((size_t)t * 64 + b_) * 1024 + u] = f2b(hv);
    }
    gridbar2(bars, lgen);
    lgen++;
    unsigned* tp = hc; hc = hn; hn = tp;
  }
  if (tid < 256) cbuf[(size_t)(bg * 16 + grow) * 1024 + cg * 16 + gul] = c_;
}

// ---------------- decoder LSTM phase (1024 thr, 4-term) ----------------
DEVINL void dec_lstm5(int bg, int cgl, int tid, char* sm,
                      const unsigned* hc, unsigned* hn,
                      const float* __restrict__ dec_emb,
                      const bf16* __restrict__ Kh, const bf16* __restrict__ Kl,
                      const float* __restrict__ dec_b, float& c_) {
  {
    int srow = tid >> 6, sj0 = (tid & 63) * 16;
    const unsigned* hrow = hc + (size_t)(bg * 16 + srow) * 1024 + sj0;
    unsigned u[16];
#pragma unroll
    for (int j = 0; j < 16; j++) u[j] = ald(hrow + j);
    int r8 = (srow & 7) << 3;
    bf16* lh = (bf16*)(sm + D_LH);
    bf16* ll = (bf16*)(sm + D_LL);
#pragma unroll
    for (int j = 0; j < 16; j += 2) {
      int es = (sj0 + j) ^ r8;
      *(unsigned*)((char*)lh + srow * 2048 + es * 2) = (u[j] >> 16) | (u[j + 1] & 0xffff0000u);
      *(unsigned*)((char*)ll + srow * 2048 + es * 2) = (u[j] & 0xffffu) | (u[j + 1] << 16);
    }
  }
  __syncthreads();
  int wv = tid >> 6, l = tid & 63, lr = l & 15, lq = l >> 4;
  int kq = wv >> 2, cs = wv & 3;
  const int* y_l = (const int*)(sm + D_YL);
  float* zs = (float*)(sm + D_ZS);
  {
    f32x4 acc = {0.f, 0.f, 0.f, 0.f};
    const bf16* bh = Kh + (size_t)(cgl * 64 + cs * 16 + lr) * 2048;
    const bf16* bl = Kl + (size_t)(cgl * 64 + cs * 16 + lr) * 2048;
    if (kq < 2) {
      const float* xr = dec_emb + (size_t)y_l[lr] * 1024 + kq * 512 + lq * 8;
#pragma unroll 4
      for (int i = 0; i < 16; i++) {
        float4 v0 = *(const float4*)(xr + i * 32);
        float4 v1 = *(const float4*)(xr + i * 32 + 4);
        float vs[8] = {v0.x, v0.y, v0.z, v0.w, v1.x, v1.y, v1.z, v1.w};
        bf8v a_h, a_l;
#pragma unroll
        for (int e = 0; e < 8; e++) {
          unsigned short uh = f2bu(vs[e]);
          a_h[e] = (short)uh;
          a_l[e] = (short)f2bu(vs[e] - us2f(uh));
        }
        int k = kq * 512 + i * 32 + lq * 8;
        bf8v b_h = *(const bf8v*)(bh + k);
        bf8v b_l = *(const bf8v*)(bl + k);
        acc = MFMA16(a_h, b_h, acc); acc = MFMA16(a_h, b_l, acc);
        acc = MFMA16(a_l, b_h, acc); acc = MFMA16(a_l, b_l, acc);
      }
    } else {
      bf16* lh = (bf16*)(sm + D_LH);
      bf16* ll = (bf16*)(sm + D_LL);
      int r8 = (lr & 7) << 3;
#pragma unroll 4
      for (int i = 0; i < 16; i++) {
        int k2 = (kq - 2) * 512 + i * 32 + lq * 8;
        int es = k2 ^ r8;
        bf8v a_h = *(const bf8v*)((char*)lh + lr * 2048 + es * 2);
        bf8v a_l = *(const bf8v*)((char*)ll + lr * 2048 + es * 2);
        int k = 1024 + k2;
        bf8v b_h = *(const bf8v*)(bh + k);
        bf8v b_l = *(const bf8v*)(bl + k);
        acc = MFMA16(a_h, b_h, acc); acc = MFMA16(a_h, b_l, acc);
        acc = MFMA16(a_l, b_h, acc); acc = MFMA16(a_l, b_l, acc);
      }
    }
#pragma unroll
    for (int r = 0; r < 4; r++) zs[(kq * 16 + lq * 4 + r) * 68 + cs * 16 + lr] = acc[r];
  }
  __syncthreads();
  if (tid < 256) {
    int grow = tid >> 4, gul = tid & 15;
    int b_ = bg * 16 + grow;
    float zz[4];
#pragma unroll
    for (int g = 0; g < 4; g++) {
      int cc = gul * 4 + g;
      int colp = cgl * 64 + cc;
      float v = zs[(0 + grow) * 68 + cc] + zs[(16 + grow) * 68 + cc] +
                zs[(32 + grow) * 68 + cc] + zs[(48 + grow) * 68 + cc];
      zz[g] = v + dec_b[(colp & 3) * 1024 + (colp >> 2)];
    }
    float iv = sigf(zz[0]), fv = sigf(zz[1]), gv = tanhf(zz[2]), ov = sigf(zz[3]);
    float cn = fv * c_ + iv * gv;
    c_ = cn;
    float hv = ov * tanhf(cn);
    unsigned short uh = f2bu(hv);
    unsigned pkv = ((unsigned)uh << 16) | (unsigned)f2bu(hv - us2f(uh));
    ast(hn + (size_t)b_ * 1024 + cgl * 16 + gul, pkv);
  }
}

// ---------------- decoder persistent kernel (1024 thr) ----------------
__global__ __launch_bounds__(1024, 4) void ed_dec_v5(
    const int* __restrict__ src,
    const bf16* __restrict__ KRh, const bf16* __restrict__ KRl, const float* __restrict__ dec_b,
    const bf16* __restrict__ WcTh, const bf16* __restrict__ WcTl, const float* __restrict__ b_cp,
    const bf16* __restrict__ WoTh, const float* __restrict__ b_op,
    const float* __restrict__ Wout_f32, const float* __restrict__ dec_emb,
    const float* __restrict__ hsf, const bf16* __restrict__ hsW,
    unsigned* hpkA, unsigned* hpkB, float* __restrict__ cbuf,
    float* __restrict__ pctx, float* __restrict__ psum, unsigned* ahpk,
    float* __restrict__ rowsum, float* __restrict__ rmax, int* __restrict__ ridx,
    float* __restrict__ out, unsigned* bars) {
  extern __shared__ char sm[];
  int bid = blockIdx.x, tid = threadIdx.x;
  int bg = bid >> 6, cgl = bid & 63;
  int wv = tid >> 6, l = tid & 63, lr = l & 15, lq = l >> 4;
  float c_ = 0.f;
  if (tid < 256) c_ = cbuf[(size_t)(bg * 16 + (tid >> 4)) * 1024 + cgl * 16 + (tid & 15)];
  unsigned *hc = hpkA, *hn = hpkB;
  unsigned lgen = 0;

  if (tid < 16) ((int*)(sm + D_YL))[tid] = 1;
  __syncthreads();
  dec_lstm5(bg, cgl, tid, sm, hc, hn, dec_emb, KRh, KRl, dec_b, c_);
  gridbar2(bars, lgen); lgen++;
  { unsigned* tp = hc; hc = hn; hn = tp; }

  for (int st = 0; st < 32; st++) {
    // ---- P1: attention scores + exp + partial ctx (fp32 hs); block = (b, kg) ----
    {
      int b_ = bid >> 2, kg = bid & 3;
      float* hbf = (float*)(sm + D_HBF);
      hbf[tid] = us2f((unsigned short)(ald(hc + (size_t)b_ * 1024 + tid) >> 16));
      __syncthreads();
      float* psc = (float*)(sm + D_PSC);
      {
        int kl = tid >> 4, q = tid & 15;
        const bf16* wrow = hsW + ((size_t)(kg * 64 + kl) * 64 + b_) * 1024 + q * 64;
        float p = 0.f;
#pragma unroll
        for (int j = 0; j < 8; j++) {
          uint4 wv_ = *(const uint4*)(wrow + j * 8);
          int kb = q * 64 + j * 8;
          p += hbf[kb + 0] * us2f(wv_.x & 0xffff) + hbf[kb + 1] * us2f(wv_.x >> 16);
          p += hbf[kb + 2] * us2f(wv_.y & 0xffff) + hbf[kb + 3] * us2f(wv_.y >> 16);
          p += hbf[kb + 4] * us2f(wv_.z & 0xffff) + hbf[kb + 5] * us2f(wv_.z >> 16);
          p += hbf[kb + 6] * us2f(wv_.w & 0xffff) + hbf[kb + 7] * us2f(wv_.w >> 16);
        }
        psc[kl * 17 + q] = p;
      }
      __syncthreads();
      float* ek = (float*)(sm + D_EK);
      if (tid < 64) {
        float sc = 0.f;
#pragma unroll
        for (int q = 0; q < 16; q++) sc += psc[tid * 17 + q];
        ek[tid] = (src[b_ * 256 + kg * 64 + tid] > 0) ? expf(sc) : 0.f;
      }
      __syncthreads();
      float* pc4 = (float*)(sm + D_PC4);
      {
        int cq = tid & 255, kc = tid >> 8;
        float a0 = 0.f, a1 = 0.f, a2 = 0.f, a3 = 0.f;
#pragma unroll 4
        for (int j = 0; j < 16; j++) {
          float e = ek[kc * 16 + j];
          const float* hr = hsf + ((size_t)(kg * 64 + kc * 16 + j) * 64 + b_) * 1024 + cq * 4;
          float4 uv = *(const float4*)hr;
          a0 += e * uv.x; a1 += e * uv.y; a2 += e * uv.z; a3 += e * uv.w;
        }
        pc4[kc * 1024 + cq * 4 + 0] = a0;
        pc4[kc * 1024 + cq * 4 + 1] = a1;
        pc4[kc * 1024 + cq * 4 + 2] = a2;
        pc4[kc * 1024 + cq * 4 + 3] = a3;
      }
      __syncthreads();
      {
        float v = pc4[tid] + pc4[1024 + tid] + pc4[2048 + tid] + pc4[3072 + tid];
        astf(pctx + ((size_t)kg * 64 + b_) * 1024 + tid, v);
      }
      if (tid == 0) {
        float* ek2 = (float*)(sm + D_EK);
        float s_ = 0.f;
        for (int i2 = 0; i2 < 64; i2++) s_ += ek2[i2];
        astf(psum + kg * 64 + b_, s_);
      }
    }
    gridbar2(bars, lgen); lgen++;
    // ---- P3: ctx-reduce + ah = tanh([ctx,h]@W_c + b_c); block = (bg, 16-col) ----
    {
      float* inv_l = (float*)(sm + D_INV);
      if (tid < 16) {
        int rb = bg * 16 + tid;
        float sg = aldf(psum + rb) + aldf(psum + 64 + rb) +
                   aldf(psum + 128 + rb) + aldf(psum + 192 + rb);
        inv_l[tid] = 1.0f / sg;
      }
      __syncthreads();
      float* zs3 = (float*)(sm + D_ZS3);
      {
        int kq = wv;
        f32x4 acc = {0.f, 0.f, 0.f, 0.f};
        const bf16* bh = WcTh + (size_t)(cgl * 16 + lr) * 2048;
        const bf16* bl = WcTl + (size_t)(cgl * 16 + lr) * 2048;
        float inv = inv_l[lr];
#pragma unroll
        for (int i = 0; i < 4; i++) {
          int k = kq * 128 + i * 32 + lq * 8;
          bf8v a_h, a_l;
          if (k < 1024) {
            const float* p0 = pctx + (size_t)(bg * 16 + lr) * 1024 + k;
#pragma unroll
            for (int e = 0; e < 8; e++) {
              float v = (aldf(p0 + e) + aldf(p0 + 65536 + e) +
                         aldf(p0 + 131072 + e) + aldf(p0 + 196608 + e)) * inv;
              unsigned short uh = f2bu(v);
              a_h[e] = (short)uh;
              a_l[e] = (short)f2bu(v - us2f(uh));
            }
          } else {
            const unsigned* hp = hc + (size_t)(bg * 16 + lr) * 1024 + (k - 1024);
#pragma unroll
            for (int e = 0; e < 8; e++) {
              unsigned u = ald(hp + e);
              a_h[e] = (short)(u >> 16);
              a_l[e] = (short)(u & 0xffffu);
            }
          }
          bf8v b_h = *(const bf8v*)(bh + k);
          bf8v b_l = *(const bf8v*)(bl + k);
          acc = MFMA16(a_h, b_h, acc); acc = MFMA16(a_h, b_l, acc);
          acc = MFMA16(a_l, b_h, acc); acc = MFMA16(a_l, b_l, acc);
        }
#pragma unroll
        for (int r = 0; r < 4; r++) zs3[(kq * 16 + lq * 4 + r) * 17 + lr] = acc[r];
      }
      __syncthreads();
      if (tid < 256) {
        int grow = tid >> 4, gcol = tid & 15;
        float v = 0.f;
#pragma unroll
        for (int q = 0; q < 16; q++) v += zs3[(q * 16 + grow) * 17 + gcol];
        v += b_cp[cgl * 16 + gcol];
        float ahv = tanhf(v);
        unsigned short uh = f2bu(ahv);
        unsigned pkv = ((unsigned)uh << 16) | (unsigned)f2bu(ahv - us2f(uh));
        ast(ahpk + (size_t)(bg * 16 + grow) * 1024 + cgl * 16 + gcol, pkv);
      }
    }
    gridbar2(bars, lgen); lgen++;
    // ---- P4: hi-only logits (LDS-staged A) + per-block exp-sum / top-2 (fp32) ----
    {
      int base = bid * 125;
      bf16* Ast = (bf16*)(sm + D_AST);
      {
        int row = tid >> 4, k0 = (tid & 15) * 64;
        const unsigned* ap = ahpk + (size_t)row * 1024 + k0;
        int r8 = (row & 7) << 3;
#pragma unroll
        for (int j = 0; j < 64; j += 2) {
          unsigned u0 = ald(ap + j), u1 = ald(ap + j + 1);
          int es = (k0 + j) ^ r8;
          *(unsigned*)((char*)Ast + row * 2048 + es * 2) = (u0 >> 16) | (u1 & 0xffff0000u);
        }
      }
      __syncthreads();
      int rg = wv >> 2, cg2 = wv & 3;
      f32x4 la0 = {0.f, 0.f, 0.f, 0.f}, la1 = {0.f, 0.f, 0.f, 0.f};
      {
        int c0 = cg2 * 32 + lr;      int cc0 = c0 < 125 ? c0 : 124;
        int c1 = cg2 * 32 + 16 + lr; int cc1 = c1 < 125 ? c1 : 124;
        const bf16* w0 = WoTh + (size_t)(base + cc0) * 1024;
        const bf16* w1 = WoTh + (size_t)(base + cc1) * 1024;
        int r8 = ((rg * 16 + lr) & 7) << 3;
#pragma unroll 4
        for (int i = 0; i < 32; i++) {
          int k = i * 32 + lq * 8;
          int es = k ^ r8;
          bf8v a_h = *(const bf8v*)((char*)Ast + (rg * 16 + lr) * 2048 + es * 2);
          la0 = MFMA16(a_h, *(const bf8v*)(w0 + k), la0);
          la1 = MFMA16(a_h, *(const bf8v*)(w1 + k), la1);
        }
      }
      __syncthreads();
      float* e = (float*)(sm + D_E);
      {
#pragma unroll
        for (int ct = 0; ct < 2; ct++) {
          int cl = cg2 * 32 + ct * 16 + lr;
          if (cl < 125) {
#pragma unroll
            for (int r = 0; r < 4; r++) {
              float lv = (ct == 0 ? la0[r] : la1[r]) + b_op[base + cl];
              e[(rg * 16 + lq * 4 + r) * 129 + cl] = lv;
            }
          }
        }
      }
      __syncthreads();
      if (tid < 64) {
        float sm_ = 0.f, v1 = -1e30f, v2 = -1e30f;
        int i1 = 0, i2 = 0;
        for (int c2 = 0; c2 < 125; c2++) {
          float v = e[tid * 129 + c2];
          sm_ += expf(v);
          if (v > v1) { v2 = v1; i2 = i1; v1 = v; i1 = base + c2; }
          else if (v > v2) { v2 = v; i2 = base + c2; }
        }
        astf(rowsum + bid * 64 + tid, sm_);
        astf(rmax + (bid * 64 + tid) * 2 + 0, v1);
        ast((unsigned*)ridx + (bid * 64 + tid) * 2 + 0, (unsigned)i1);
        astf(rmax + (bid * 64 + tid) * 2 + 1, v2);
        ast((unsigned*)ridx + (bid * 64 + tid) * 2 + 1, (unsigned)i2);
      }
    }
    gridbar2(bars, lgen); lgen++;
    // ---- P5: probs write + candidate refine (f64) + next LSTM ----
    {
      float* psc2 = (float*)(sm + D_PSC2);
      {
        int rr = tid & 63, pp = tid >> 6;
        float s_ = 0.f;
#pragma unroll 4
        for (int cu = pp * 16; cu < pp * 16 + 16; cu++) s_ += aldf(rowsum + cu * 64 + rr);
        psc2[rr * 17 + pp] = s_;
      }
      __syncthreads();
      float* rt = (float*)(sm + D_RT);
      if (tid < 64) {
        float s_ = 0.f;
#pragma unroll
        for (int p2 = 0; p2 < 16; p2++) s_ += psc2[tid * 17 + p2];
        rt[tid] = s_;
      }
      __syncthreads();
      float* e = (float*)(sm + D_E);
      {
        int base = bid * 125;
        for (int i = tid; i < 8000; i += 1024) {
          int r_ = i / 125, c2 = i - r_ * 125;
          out[((size_t)r_ * 32 + st) * 32000 + base + c2] = expf(e[r_ * 129 + c2]) / rt[r_];
        }
      }
      if (st < 31) {
        float* gmx = (float*)(sm + D_GMX);
        int* ccnt = (int*)(sm + D_CCN);
        int* cand = (int*)(sm + D_CAND);
        int* y_l = (int*)(sm + D_YL);
        int r16 = tid & 15, ch = tid >> 4;
        int rowg = bg * 16 + r16;
        float vloc[8]; int iloc[8];
        {
          float m_ = -1e30f;
#pragma unroll
          for (int ee = 0; ee < 8; ee++) {
            int ent = ch * 8 + ee;
            vloc[ee] = aldf(rmax + ((size_t)(ent >> 1) * 64 + rowg) * 2 + (ent & 1));
            iloc[ee] = (int)ald((const unsigned*)ridx + ((size_t)(ent >> 1) * 64 + rowg) * 2 + (ent & 1));
            m_ = fmaxf(m_, vloc[ee]);
          }
          gmx[r16 * 65 + ch] = m_;
        }
        if (tid < 16) ccnt[tid] = 0;
        __syncthreads();
        if (tid < 16) {
          float g_ = -1e30f;
#pragma unroll
          for (int j = 0; j < 64; j++) g_ = fmaxf(g_, gmx[tid * 65 + j]);
          gmx[tid * 65 + 64] = g_;
        }
        __syncthreads();
        {
          float thr = gmx[r16 * 65 + 64] - DELTA;
#pragma unroll
          for (int ee = 0; ee < 8; ee++) {
            if (vloc[ee] >= thr) {
              int slot = atomicAdd(&ccnt[r16], 1);
              if (slot < 8) cand[r16 * 8 + slot] = iloc[ee];
            }
          }
        }
        __syncthreads();
        {
          int row2 = wv;
          int rowg2 = bg * 16 + row2;
          int cnt = ccnt[row2]; if (cnt > 8) cnt = 8;
          double bv = -1e30; int bi_ = 0x7fffffff;
          for (int ci = 0; ci < cnt; ci++) {
            int c = cand[row2 * 8 + ci];
            double s_ = 0.0;
            for (int k = l; k < 1024; k += 64) {
              unsigned u = ald(ahpk + (size_t)rowg2 * 1024 + k);
              float av = us2f((unsigned short)(u >> 16)) + us2f((unsigned short)(u & 0xffffu));
              s_ += (double)av * (double)Wout_f32[(size_t)k * 32000 + c];
            }
#pragma unroll
            for (int off = 32; off > 0; off >>= 1) s_ += __shfl_down(s_, off);
            if (l == 0) {
              s_ += (double)b_op[c];
              if (s_ > bv || (s_ == bv && c < bi_)) { bv = s_; bi_ = c; }
            }
          }
          if (l == 0) y_l[row2] = bi_;
        }
        __syncthreads();
        dec_lstm5(bg, cgl, tid, sm, hc, hn, dec_emb, KRh, KRl, dec_b, c_);
      }
    }
    gridbar2(bars, lgen); lgen++;
    { unsigned* tp = hc; hc = hn; hn = tp; }
  }
}

// ---------------- host launch ----------------
extern "C" void kernel_launch(void* const* d_in, const int* in_sizes, int n_in,
                              void* d_out, int out_size, void* d_ws, size_t ws_size,
                              hipStream_t stream) {
  (void)in_sizes; (void)n_in; (void)out_size; (void)ws_size;
  const int*   src     = (const int*)  d_in[0];
  const float* enc_emb = (const float*)d_in[1];
  const float* enc_K   = (const float*)d_in[2];
  const float* enc_R   = (const float*)d_in[3];
  const float* enc_b   = (const float*)d_in[4];
  const float* dec_emb = (const float*)d_in[5];
  const float* dec_K   = (const float*)d_in[6];
  const float* dec_R   = (const float*)d_in[7];
  const float* dec_b   = (const float*)d_in[8];
  const float* W_a     = (const float*)d_in[9];
  const float* W_c     = (const float*)d_in[10];
  const float* b_c     = (const float*)d_in[11];
  const float* W_out   = (const float*)d_in[12];
  const float* b_out   = (const float*)d_in[13];
  char* ws = (char*)d_ws;

  hipFuncSetAttribute((const void*)ed_enc_v5, hipFuncAttributeMaxDynamicSharedMemorySize, 163840);
  hipFuncSetAttribute((const void*)ed_dec_v5, hipFuncAttributeMaxDynamicSharedMemorySize, 163840);

  bf16* KpTh = (bf16*)(ws + OKPT_H);
  bf16* KpTl = (bf16*)(ws + OKPT_L);
  bf16* RpTh = (bf16*)(ws + ORPT_H);
  bf16* RpTl = (bf16*)(ws + ORPT_L);
  bf16* WaT  = (bf16*)(ws + OWAT);
  bf16* xeh  = (bf16*)(ws + OXE_H);
  bf16* xel  = (bf16*)(ws + OXE_L);
  float* hsf = (float*)(ws + OHSF5);
  bf16* hsb  = (bf16*)(ws + OHSB5);
  unsigned* hpkE0 = (unsigned*)(ws + OHPK_E0);
  unsigned* hpkE1 = (unsigned*)(ws + OHPK_E1);
  unsigned* hpkD0 = (unsigned*)(ws + OHPK_D0);
  float* cbuf = (float*)(ws + OCBUF5);
  unsigned* ahpk = (unsigned*)(ws + OAHPK);
  float* rsum = (float*)(ws + ORSUM5);
  float* rmaxp = (float*)(ws + ORMAX5);
  int*  ridxp = (int*)(ws + ORIDX5);
  float* psum = (float*)(ws + OPSUM5);
  unsigned* bars = (unsigned*)(ws + OBARS5);
  bf16* XkL  = (bf16*)(ws + OXK_L5);
  bf16* XkH  = (bf16*)d_out;
  bf16* WcTh = (bf16*)(ws + OWCT_H);
  bf16* WcTl = (bf16*)(ws + OWCT_L);
  float* pctx = (float*)(ws + OPCTX5);
  bf16* WoTh = (bf16*)(ws + OWOT5);
  bf16* KRTh = (bf16*)(ws + OKRTH5);
  bf16* KRTl = (bf16*)(ws + OKRTL5);
  bf16* hsW  = (bf16*)(ws + OHSW5);

  // zero exchange zone (h bufs, cbuf, ahpk, reductions, barriers)
  ed_zero_v5<<<512, 256, 0, stream>>>((float4*)(ws + XCH), 131072);
  // stage-A weight prep
  ed_transpose_split_v5<<<dim3(128, 32), 256, 0, stream>>>(enc_K, KpTh, KpTl, 1024, 4096, 1024, 0, 1);
  ed_transpose_split_v5<<<dim3(128, 32), 256, 0, stream>>>(enc_R, RpTh, RpTl, 1024, 4096, 1024, 0, 1);
  ed_transpose_v5<<<dim3(32, 32), 256, 0, stream>>>(W_a, WaT, 1024, 1024, 1024, 0, 0);
  ed_gather_split_v5<<<16384, 256, 0, stream>>>(src, enc_emb, xeh, xel);
  // Xk = xe @ enc_K (split), hi -> d_out, lo -> ws
  ed_gemm3_v5<<<dim3(32, 128), 256, 0, stream>>>(xeh, xel, KpTh, KpTl, XkH, XkL, 16384, 4096, 1024);
  // WcT over dead KpT (safe: encoder does not touch [0,16M))
  ed_transpose_split_v5<<<dim3(32, 64), 256, 0, stream>>>(W_c, WcTh, WcTl, 2048, 1024, 2048, 0, 0);
  // encoder recurrence (hsf fp32 over dead xe region)
  ed_enc_v5<<<256, 1024, 87040, stream>>>(src, RpTh, RpTl, XkH, XkL, enc_b,
                                          hpkE0, hpkE1, cbuf, hsf, hsb, bars);
  // post-encoder prep into dead-Xk region
  ed_transpose_v5<<<dim3(1000, 32), 256, 0, stream>>>(W_out, WoTh, 1024, 32000, 1024, 0, 0);
  ed_transpose_split_v5<<<dim3(128, 32), 256, 0, stream>>>(dec_K, KRTh, KRTl, 1024, 4096, 2048, 0, 1);
  ed_transpose_split_v5<<<dim3(128, 32), 256, 0, stream>>>(dec_R, KRTh, KRTl, 1024, 4096, 2048, 1024, 1);
  ed_gemm_bt_v5<<<dim3(8, 128), 256, 0, stream>>>(hsb, WaT, hsW, 16384, 1024, 1024);
  // decoder (initial h = encoder final h in hpkE0)
  ed_dec_v5<<<256, 1024, 131456, stream>>>(src, KRTh, KRTl, dec_b, WcTh, WcTl, b_c,
                                           WoTh, b_out, W_out, dec_emb, hsf, hsW,
                                           hpkE0, hpkD0, cbuf, pctx, psum, ahpk,
                                           rsum, rmaxp, ridxp, (float*)d_out, bars + 512);
}

// Round 6
// 13896.231 us; speedup vs baseline: 2.2544x; 1.0873x over previous
//
#include <hip/hip_runtime.h>
#include <hip/hip_bf16.h>

typedef __hip_bfloat16 bf16;
typedef short bf8v __attribute__((ext_vector_type(8)));   // 8 x bf16 (4 VGPR)
typedef float f32x4 __attribute__((ext_vector_type(4)));

#define DEVINL __device__ __forceinline__
#define MFMA16(a, b, c) __builtin_amdgcn_mfma_f32_16x16x32_bf16((a), (b), (c), 0, 0, 0)

DEVINL float us2f(unsigned short u) { unsigned v = ((unsigned)u) << 16; return __uint_as_float(v); }
DEVINL float b2f(bf16 x) { return __bfloat162float(x); }
DEVINL bf16 f2b(float x) { return __float2bfloat16(x); }
DEVINL float sigf(float x) { return 1.0f / (1.0f + expf(-x)); }
DEVINL unsigned short f2bu(float f) { bf16 h = __float2bfloat16(f); return *(unsigned short*)&h; }

DEVINL void gload16(const void* g, void* l) {
  __builtin_amdgcn_global_load_lds((const __attribute__((address_space(1))) void*)g,
                                   (__attribute__((address_space(3))) void*)l, 16, 0, 0);
}

// ---- relaxed agent-scope atomics ----
DEVINL unsigned ald(const unsigned* p) {
  return __hip_atomic_load(p, __ATOMIC_RELAXED, __HIP_MEMORY_SCOPE_AGENT);
}
DEVINL void ast(unsigned* p, unsigned v) {
  __hip_atomic_store(p, v, __ATOMIC_RELAXED, __HIP_MEMORY_SCOPE_AGENT);
}
DEVINL float aldf(const float* p) { unsigned u = ald((const unsigned*)p); return __uint_as_float(u); }
DEVINL void astf(float* p, float v) { ast((unsigned*)p, __float_as_uint(v)); }

// ---- global 256-block barrier (8 groups x 32), parity-buffered ----
DEVINL void gridbar2(unsigned* bars, unsigned lgen) {
  __syncthreads();
  if (threadIdx.x == 0) {
    unsigned s = lgen & 1;
    unsigned g = blockIdx.x >> 5;
    unsigned* grp = bars + (g * 2 + s) * 16;
    unsigned* top = bars + (16 + s) * 16;
    unsigned* gen = bars + 288;
    unsigned t = __hip_atomic_fetch_add(grp, 1u, __ATOMIC_RELAXED, __HIP_MEMORY_SCOPE_AGENT);
    if (t == 31u) {
      ast(grp, 0u);
      unsigned tt = __hip_atomic_fetch_add(top, 1u, __ATOMIC_RELAXED, __HIP_MEMORY_SCOPE_AGENT);
      if (tt == 7u) {
        ast(top, 0u);
        asm volatile("s_waitcnt vmcnt(0)");
        ast(gen, lgen + 1u);
      }
    }
    while (ald(gen) <= lgen) __builtin_amdgcn_s_sleep(4);
  }
  __syncthreads();
}

// ---- local 64-block barrier (2 groups x 32); b = per-group base (97 u32 used) ----
DEVINL void bar64(unsigned* b, unsigned lgen, int lid) {
  __syncthreads();
  if (threadIdx.x == 0) {
    unsigned s = lgen & 1;
    unsigned* grp = b + (((unsigned)(lid >> 5) & 1u) * 2 + s) * 16;
    unsigned* top = b + (4 + s) * 16;
    unsigned* gen = b + 96;
    unsigned t = __hip_atomic_fetch_add(grp, 1u, __ATOMIC_RELAXED, __HIP_MEMORY_SCOPE_AGENT);
    if (t == 31u) {
      ast(grp, 0u);
      unsigned tt = __hip_atomic_fetch_add(top, 1u, __ATOMIC_RELAXED, __HIP_MEMORY_SCOPE_AGENT);
      if (tt == 1u) {
        ast(top, 0u);
        asm volatile("s_waitcnt vmcnt(0)");
        ast(gen, lgen + 1u);
      }
    }
    while (ald(gen) <= lgen) __builtin_amdgcn_s_sleep(2);
  }
  __syncthreads();
}

// ---------------- ws layout (bytes); total <= 272,629,760 ----
#define OKPT_H  ((size_t)0)
#define OKPT_L  ((size_t)8388608)
#define ORPT_H  ((size_t)16777216)
#define ORPT_L  ((size_t)25165824)
#define OWAT    ((size_t)33554432)
#define OXE_H   ((size_t)35651584)
#define OXE_L   ((size_t)69206016)
#define OHSF5   ((size_t)35651584)
#define OHSB5   ((size_t)102760448)
#define XCH     ((size_t)136314880)
#define OHPK_E0 (XCH + 0)
#define OHPK_E1 (XCH + 262144)
#define OHPK_D0 (XCH + 524288)
#define OCBUF5  (XCH + 1048576)
#define OAHPK   (XCH + 1310720)
#define ORSUM5  (XCH + 1572864)
#define ORMAX5  (XCH + 1638400)
#define ORIDX5  (XCH + 1769472)
#define OPSUM5  (XCH + 1900544)
#define OBARS5  (XCH + 1901568)
#define OXK_L5  ((size_t)138412032)
#define OWCT_H  ((size_t)0)
#define OWCT_L  ((size_t)4194304)
#define OPCTX5  ((size_t)8388608)
#define OWOT5   ((size_t)138412032)
#define OKRTH5  ((size_t)203948032)
#define OKRTL5  ((size_t)220725248)
#define OHSW5   ((size_t)237502464)

#define DELTA   1e-4f

// decoder LDS pool offsets (pool 150528)
#define D_LH   0
#define D_LL   32768
#define D_ZS   65536
#define D_KBH  83968
#define D_KBL  116736
#define D4_A   0
#define D4_W   16384
#define D4_E   49152
#define D_HBF  0
#define D_PSC  4096
#define D_EK   8448
#define D_PC4  8704
#define D_ZS3  0
#define D_PSC2 0
#define D_GMX  4352
#define D_CCN  8512
#define D_CAND 8576
#define D_YL   149504
#define D_INV  149568
#define D_RT   149632

// ---------------- utility kernels ----------------
__global__ void ed_zero_v6(float4* p, int n) {
  int i = blockIdx.x * 256 + threadIdx.x;
  if (i < n) p[i] = make_float4(0.f, 0.f, 0.f, 0.f);
}

__global__ void ed_transpose_v6(const float* __restrict__ in, bf16* __restrict__ out,
                                int R, int C, int ostride, int ooff, int perm) {
  __shared__ float tile[32][33];
  int c0 = blockIdx.x * 32, r0 = blockIdx.y * 32;
  int tx = threadIdx.x & 31, ty0 = threadIdx.x >> 5;
#pragma unroll
  for (int i = 0; i < 4; i++) {
    int ty = ty0 + i * 8;
    tile[ty][tx] = in[(size_t)(r0 + ty) * C + c0 + tx];
  }
  __syncthreads();
#pragma unroll
  for (int i = 0; i < 4; i++) {
    int ty = ty0 + i * 8;
    int c = c0 + ty;
    int oc = perm ? ((c & 1023) * 4 + (c >> 10)) : c;
    out[(size_t)oc * ostride + ooff + r0 + tx] = f2b(tile[tx][ty]);
  }
}

__global__ void ed_transpose_split_v6(const float* __restrict__ in, bf16* __restrict__ oh,
                                      bf16* __restrict__ ol, int R, int C, int ostride,
                                      int ooff, int perm) {
  __shared__ float tile[32][33];
  int c0 = blockIdx.x * 32, r0 = blockIdx.y * 32;
  int tx = threadIdx.x & 31, ty0 = threadIdx.x >> 5;
#pragma unroll
  for (int i = 0; i < 4; i++) {
    int ty = ty0 + i * 8;
    tile[ty][tx] = in[(size_t)(r0 + ty) * C + c0 + tx];
  }
  __syncthreads();
#pragma unroll
  for (int i = 0; i < 4; i++) {
    int ty = ty0 + i * 8;
    int c = c0 + ty;
    int oc = perm ? ((c & 1023) * 4 + (c >> 10)) : c;
    float v = tile[tx][ty];
    bf16 hh = f2b(v);
    size_t o = (size_t)oc * ostride + ooff + r0 + tx;
    oh[o] = hh;
    ol[o] = f2b(v - b2f(hh));
  }
}

__global__ void ed_gather_split_v6(const int* __restrict__ src, const float* __restrict__ emb,
                                   bf16* __restrict__ xh, bf16* __restrict__ xl) {
  int bid = blockIdx.x;
  int t = bid >> 6, b = bid & 63;
  int tok = src[b * 256 + t];
  const float* rowp = emb + (size_t)tok * 1024;
  int i = threadIdx.x * 4;
  float4 v = *(const float4*)(rowp + i);
  bf16 h0 = f2b(v.x), h1 = f2b(v.y), h2 = f2b(v.z), h3 = f2b(v.w);
  ushort4 oh, ol;
  oh.x = *(unsigned short*)&h0; oh.y = *(unsigned short*)&h1;
  oh.z = *(unsigned short*)&h2; oh.w = *(unsigned short*)&h3;
  ol.x = f2bu(v.x - b2f(h0)); ol.y = f2bu(v.y - b2f(h1));
  ol.z = f2bu(v.z - b2f(h2)); ol.w = f2bu(v.w - b2f(h3));
  *(ushort4*)(xh + (size_t)bid * 1024 + i) = oh;
  *(ushort4*)(xl + (size_t)bid * 1024 + i) = ol;
}

// ---------------- plain bf16 GEMM (hsW only) ----------------
__global__ __launch_bounds__(256, 2) void ed_gemm_bt_v6(
    const bf16* __restrict__ A, const bf16* __restrict__ BT, bf16* __restrict__ C,
    int M, int N, int K) {
  __shared__ __align__(16) bf16 As[128 * 32];
  __shared__ __align__(16) bf16 Bs[128 * 32];
  int m0 = blockIdx.y * 128, n0 = blockIdx.x * 128;
  int tid = threadIdx.x, w = tid >> 6, l = tid & 63;
  int wm = w >> 1, wn = w & 1;
  int lr = l & 15, lq = l >> 4;
  f32x4 acc[4][4] = {};
  for (int k0 = 0; k0 < K; k0 += 32) {
    __syncthreads();
#pragma unroll
    for (int j = 0; j < 2; j++) {
      int o = (w * 2 + j) * 1024 + l * 16;
      int rrow = o >> 6, kk = (o & 63) >> 1;
      gload16(A + (size_t)(m0 + rrow) * K + k0 + kk, (char*)As + (w * 2 + j) * 1024);
      gload16(BT + (size_t)(n0 + rrow) * K + k0 + kk, (char*)Bs + (w * 2 + j) * 1024);
    }
    __syncthreads();
#pragma unroll
    for (int mi = 0; mi < 4; mi++) {
      bf8v a = *(const bf8v*)(As + (wm * 64 + mi * 16 + lr) * 32 + lq * 8);
#pragma unroll
      for (int ni = 0; ni < 4; ni++) {
        bf8v b = *(const bf8v*)(Bs + (wn * 64 + ni * 16 + lr) * 32 + lq * 8);
        acc[mi][ni] = MFMA16(a, b, acc[mi][ni]);
      }
    }
  }
#pragma unroll
  for (int mi = 0; mi < 4; mi++)
#pragma unroll
    for (int ni = 0; ni < 4; ni++)
#pragma unroll
      for (int r = 0; r < 4; r++)
        C[(size_t)(m0 + wm * 64 + mi * 16 + lq * 4 + r) * N + n0 + wn * 64 + ni * 16 + lr] =
            f2b(acc[mi][ni][r]);
}

// ---------------- split-precision GEMM (3-term), split output (Xk) ----------------
__global__ __launch_bounds__(256, 2) void ed_gemm3_v6(
    const bf16* __restrict__ Ah, const bf16* __restrict__ Al,
    const bf16* __restrict__ Bh, const bf16* __restrict__ Bl,
    bf16* __restrict__ Ch, bf16* __restrict__ Cl, int M, int N, int K) {
  __shared__ __align__(16) bf16 Ash[128 * 32];
  __shared__ __align__(16) bf16 Asl[128 * 32];
  __shared__ __align__(16) bf16 Bsh[128 * 32];
  __shared__ __align__(16) bf16 Bsl[128 * 32];
  int m0 = blockIdx.y * 128, n0 = blockIdx.x * 128;
  int tid = threadIdx.x, w = tid >> 6, l = tid & 63;
  int wm = w >> 1, wn = w & 1;
  int lr = l & 15, lq = l >> 4;
  f32x4 acc[4][4] = {};
  for (int k0 = 0; k0 < K; k0 += 32) {
    __syncthreads();
#pragma unroll
    for (int j = 0; j < 2; j++) {
      int o = (w * 2 + j) * 1024 + l * 16;
      int rrow = o >> 6, kk = (o & 63) >> 1;
      gload16(Ah + (size_t)(m0 + rrow) * K + k0 + kk, (char*)Ash + (w * 2 + j) * 1024);
      gload16(Al + (size_t)(m0 + rrow) * K + k0 + kk, (char*)Asl + (w * 2 + j) * 1024);
      gload16(Bh + (size_t)(n0 + rrow) * K + k0 + kk, (char*)Bsh + (w * 2 + j) * 1024);
      gload16(Bl + (size_t)(n0 + rrow) * K + k0 + kk, (char*)Bsl + (w * 2 + j) * 1024);
    }
    __syncthreads();
#pragma unroll
    for (int mi = 0; mi < 4; mi++) {
      bf8v a_h = *(const bf8v*)(Ash + (wm * 64 + mi * 16 + lr) * 32 + lq * 8);
      bf8v a_l = *(const bf8v*)(Asl + (wm * 64 + mi * 16 + lr) * 32 + lq * 8);
#pragma unroll
      for (int ni = 0; ni < 4; ni++) {
        bf8v b_h = *(const bf8v*)(Bsh + (wn * 64 + ni * 16 + lr) * 32 + lq * 8);
        bf8v b_l = *(const bf8v*)(Bsl + (wn * 64 + ni * 16 + lr) * 32 + lq * 8);
        acc[mi][ni] = MFMA16(a_h, b_h, acc[mi][ni]);
        acc[mi][ni] = MFMA16(a_h, b_l, acc[mi][ni]);
        acc[mi][ni] = MFMA16(a_l, b_h, acc[mi][ni]);
      }
    }
  }
#pragma unroll
  for (int mi = 0; mi < 4; mi++)
#pragma unroll
    for (int ni = 0; ni < 4; ni++)
#pragma unroll
      for (int r = 0; r < 4; r++) {
        float v = acc[mi][ni][r];
        bf16 hh = f2b(v);
        size_t idx = (size_t)(m0 + wm * 64 + mi * 16 + lq * 4 + r) * N + n0 + wn * 64 + ni * 16 + lr;
        Ch[idx] = hh;
        Cl[idx] = f2b(v - b2f(hh));
      }
}

// ---------------- encoder: per-bg local barriers, NT Xk/hs ----------------
__global__ __launch_bounds__(1024, 4) void ed_enc_v6(
    const int* __restrict__ src, const bf16* __restrict__ Rh, const bf16* __restrict__ Rl,
    const bf16* __restrict__ Xh, const bf16* __restrict__ Xl, const float* __restrict__ enc_b,
    unsigned* hpk0, unsigned* hpk1, float* __restrict__ cbuf,
    float* __restrict__ hsf, bf16* __restrict__ hsb, unsigned* barsE) {
  extern __shared__ char sm[];
  bf16* lh = (bf16*)sm;
  bf16* ll = (bf16*)(sm + 32768);
  float* zs = (float*)(sm + 65536);
  float* xkf = (float*)(sm + 82944);
  int bid = blockIdx.x, tid = threadIdx.x;
  int bg = bid >> 6, cg = bid & 63, lid = bid & 63;
  unsigned* barL = barsE + bg * 128;
  int wv = tid >> 6, l = tid & 63, lr = l & 15, lq = l >> 4;
  int kq = wv >> 2, cs = wv & 3;
  int srow = tid >> 6, sj0 = (tid & 63) * 16;
  int grow = tid >> 4, gul = tid & 15;
  bf8v Rh_[8], Rl_[8];
  {
    const bf16* bh = Rh + (size_t)(cg * 64 + cs * 16 + lr) * 1024 + kq * 256 + lq * 8;
    const bf16* bl = Rl + (size_t)(cg * 64 + cs * 16 + lr) * 1024 + kq * 256 + lq * 8;
#pragma unroll
    for (int i = 0; i < 8; i++) {
      Rh_[i] = *(const bf8v*)(bh + i * 32);
      Rl_[i] = *(const bf8v*)(bl + i * 32);
    }
  }
  float bi[4];
  float c_ = 0.f;
  if (tid < 256) {
#pragma unroll
    for (int g = 0; g < 4; g++) {
      int colp = cg * 64 + gul * 4 + g;
      bi[g] = enc_b[(colp & 3) * 1024 + (colp >> 2)];
    }
  }
  unsigned *hc = hpk0, *hn = hpk1;
  unsigned lgen = 0;
  for (int t = 0; t < 256; t++) {
    {
      const unsigned* hrow = hc + (size_t)(bg * 16 + srow) * 1024 + sj0;
      unsigned u[16];
#pragma unroll
      for (int j = 0; j < 16; j++) u[j] = ald(hrow + j);
      int r8 = (srow & 7) << 3;
#pragma unroll
      for (int j = 0; j < 16; j += 2) {
        int es = (sj0 + j) ^ r8;
        *(unsigned*)((char*)lh + srow * 2048 + es * 2) = (u[j] >> 16) | (u[j + 1] & 0xffff0000u);
        *(unsigned*)((char*)ll + srow * 2048 + es * 2) = (u[j] & 0xffffu) | (u[j + 1] << 16);
      }
    }
    {
      int xr = tid >> 6, xc = tid & 63;
      size_t xi = ((size_t)t * 64 + bg * 16 + xr) * 4096 + cg * 64 + xc;
      unsigned short xh = __builtin_nontemporal_load((const unsigned short*)(Xh + xi));
      unsigned short xl = __builtin_nontemporal_load((const unsigned short*)(Xl + xi));
      xkf[xr * 64 + xc] = us2f(xh) + us2f(xl);
    }
    __syncthreads();
    {
      f32x4 acc = {0.f, 0.f, 0.f, 0.f};
      int r8 = (lr & 7) << 3;
#pragma unroll
      for (int i = 0; i < 8; i++) {
        int e0 = kq * 256 + i * 32 + lq * 8;
        int es = e0 ^ r8;
        bf8v a_h = *(const bf8v*)((char*)lh + lr * 2048 + es * 2);
        bf8v a_l = *(const bf8v*)((char*)ll + lr * 2048 + es * 2);
        acc = MFMA16(a_h, Rh_[i], acc);
        acc = MFMA16(a_h, Rl_[i], acc);
        acc = MFMA16(a_l, Rh_[i], acc);
        acc = MFMA16(a_l, Rl_[i], acc);
      }
#pragma unroll
      for (int r = 0; r < 4; r++) zs[(kq * 16 + lq * 4 + r) * 68 + cs * 16 + lr] = acc[r];
    }
    __syncthreads();
    if (tid < 256) {
      int b_ = bg * 16 + grow, u = cg * 16 + gul;
      float zz[4];
#pragma unroll
      for (int g = 0; g < 4; g++) {
        int cc = gul * 4 + g;
        zz[g] = zs[(0 + grow) * 68 + cc] + zs[(16 + grow) * 68 + cc] +
                zs[(32 + grow) * 68 + cc] + zs[(48 + grow) * 68 + cc] +
                xkf[grow * 64 + cc] + bi[g];
      }
      float iv = sigf(zz[0]), fv = sigf(zz[1]), gv = tanhf(zz[2]), ov = sigf(zz[3]);
      float cn = fv * c_ + iv * gv;
      float hnv = ov * tanhf(cn);
      bool m = src[b_ * 256 + t] > 0;
      int es = u ^ ((grow & 7) << 3);
      float hold = b2f(*(const bf16*)((char*)lh + grow * 2048 + es * 2)) +
                   b2f(*(const bf16*)((char*)ll + grow * 2048 + es * 2));
      float hv = m ? hnv : hold;
      c_ = m ? cn : c_;
      unsigned short uh = f2bu(hv);
      unsigned pkv = ((unsigned)uh << 16) | (unsigned)f2bu(hv - us2f(uh));
      ast(hn + (size_t)b_ * 1024 + u, pkv);
      __builtin_nontemporal_store(hv, hsf + ((size_t)t * 64 + b_) * 1024 + u);
      __builtin_nontemporal_store(f2bu(hv), (unsigned short*)(hsb + ((size_t)t * 64 + b_) * 1024 + u));
    }
    bar64(barL, lgen, lid);
    lgen++;
    unsigned* tp = hc; hc = hn; hn = tp;
  }
  if (tid < 256) cbuf[(size_t)(bg * 16 + grow) * 1024 + cg * 16 + gul] = c_;
}

// ---------------- decoder LSTM (chunked KRT staging via gload16) ----------------
DEVINL void dec_lstm6(int bg, int cgl, int tid, char* sm,
                      const unsigned* hc, unsigned* hn,
                      const float* __restrict__ dec_emb,
                      const bf16* __restrict__ Kh, const bf16* __restrict__ Kl,
                      const float* __restrict__ dec_b, float& c_) {
  bf16* lh = (bf16*)(sm + D_LH);
  bf16* ll = (bf16*)(sm + D_LL);
  // stage h: wave w owns row w; lane covers 16 packed u32 (32B hi + 32B lo out)
  {
    int srow = tid >> 6, sl = tid & 63;
    const unsigned* hrow = hc + (size_t)(bg * 16 + srow) * 1024 + sl * 16;
    unsigned u[16];
#pragma unroll
    for (int j = 0; j < 16; j++) u[j] = ald(hrow + j);
    uint4 ha, hb, la, lb;
    ha.x = (u[0] >> 16) | (u[1] & 0xffff0000u);  ha.y = (u[2] >> 16) | (u[3] & 0xffff0000u);
    ha.z = (u[4] >> 16) | (u[5] & 0xffff0000u);  ha.w = (u[6] >> 16) | (u[7] & 0xffff0000u);
    hb.x = (u[8] >> 16) | (u[9] & 0xffff0000u);  hb.y = (u[10] >> 16) | (u[11] & 0xffff0000u);
    hb.z = (u[12] >> 16) | (u[13] & 0xffff0000u); hb.w = (u[14] >> 16) | (u[15] & 0xffff0000u);
    la.x = (u[0] & 0xffffu) | (u[1] << 16);  la.y = (u[2] & 0xffffu) | (u[3] << 16);
    la.z = (u[4] & 0xffffu) | (u[5] << 16);  la.w = (u[6] & 0xffffu) | (u[7] << 16);
    lb.x = (u[8] & 0xffffu) | (u[9] << 16);  lb.y = (u[10] & 0xffffu) | (u[11] << 16);
    lb.z = (u[12] & 0xffffu) | (u[13] << 16); lb.w = (u[14] & 0xffffu) | (u[15] << 16);
    int swz = (srow & 7) << 4;
    char* rbh = (char*)lh + srow * 2048;
    char* rbl = (char*)ll + srow * 2048;
    *(uint4*)(rbh + ((sl * 32) ^ swz)) = ha;
    *(uint4*)(rbh + ((sl * 32 + 16) ^ swz)) = hb;
    *(uint4*)(rbl + ((sl * 32) ^ swz)) = la;
    *(uint4*)(rbl + ((sl * 32 + 16) ^ swz)) = lb;
  }
  int wv = tid >> 6, l = tid & 63, lr = l & 15, lq = l >> 4;
  int kg2 = wv >> 2, cs = wv & 3;
  bf16* kbh = (bf16*)(sm + D_KBH);
  bf16* kbl = (bf16*)(sm + D_KBL);
  const int* y_l = (const int*)(sm + D_YL);
  float* zs = (float*)(sm + D_ZS);
  f32x4 acc = {0.f, 0.f, 0.f, 0.f};
  int colB = cs * 16 + lr;
  int bswz = (colB & 7) << 4;
  int aswz = (lr & 7) << 4;
  for (int c = 0; c < 8; c++) {
    __syncthreads();
#pragma unroll
    for (int r = 0; r < 2; r++) {
      int i = wv * 128 + r * 64 + l;
      int col = i >> 5, j = i & 31;
      size_t se = (size_t)(cgl * 64 + col) * 2048 + c * 256 + ((size_t)(j ^ (col & 7)) << 3);
      gload16(Kh + se, (char*)kbh + wv * 2048 + r * 1024);
      gload16(Kl + se, (char*)kbl + wv * 2048 + r * 1024);
    }
    __syncthreads();
#pragma unroll
    for (int s = 0; s < 2; s++) {
      int kl = kg2 * 64 + s * 32 + lq * 8;
      bf8v b_h = *(const bf8v*)((char*)kbh + colB * 512 + ((kl * 2) ^ bswz));
      bf8v b_l = *(const bf8v*)((char*)kbl + colB * 512 + ((kl * 2) ^ bswz));
      int gk = c * 256 + kl;
      bf8v a_h, a_l;
      if (gk < 1024) {
        const float* xr = dec_emb + (size_t)y_l[lr] * 1024 + gk;
        float4 v0 = *(const float4*)xr;
        float4 v1 = *(const float4*)(xr + 4);
        float vs[8] = {v0.x, v0.y, v0.z, v0.w, v1.x, v1.y, v1.z, v1.w};
#pragma unroll
        for (int e = 0; e < 8; e++) {
          unsigned short uh = f2bu(vs[e]);
          a_h[e] = (short)uh;
          a_l[e] = (short)f2bu(vs[e] - us2f(uh));
        }
      } else {
        int hk = gk - 1024;
        a_h = *(const bf8v*)((char*)lh + lr * 2048 + ((hk * 2) ^ aswz));
        a_l = *(const bf8v*)((char*)ll + lr * 2048 + ((hk * 2) ^ aswz));
      }
      acc = MFMA16(a_h, b_h, acc);
      acc = MFMA16(a_h, b_l, acc);
      acc = MFMA16(a_l, b_h, acc);
      acc = MFMA16(a_l, b_l, acc);
    }
  }
#pragma unroll
  for (int r = 0; r < 4; r++) zs[(kg2 * 16 + lq * 4 + r) * 68 + cs * 16 + lr] = acc[r];
  __syncthreads();
  if (tid < 256) {
    int grow = tid >> 4, gul = tid & 15;
    int b_ = bg * 16 + grow;
    float zz[4];
#pragma unroll
    for (int g = 0; g < 4; g++) {
      int cc = gul * 4 + g;
      int colp = cgl * 64 + cc;
      float v = zs[(0 + grow) * 68 + cc] + zs[(16 + grow) * 68 + cc] +
                zs[(32 + grow) * 68 + cc] + zs[(48 + grow) * 68 + cc];
      zz[g] = v + dec_b[(colp & 3) * 1024 + (colp >> 2)];
    }
    float iv = sigf(zz[0]), fv = sigf(zz[1]), gv = tanhf(zz[2]), ov = sigf(zz[3]);
    float cn = fv * c_ + iv * gv;
    c_ = cn;
    float hv = ov * tanhf(cn);
    unsigned short uh = f2bu(hv);
    unsigned pkv = ((unsigned)uh << 16) | (unsigned)f2bu(hv - us2f(uh));
    ast(hn + (size_t)b_ * 1024 + cgl * 16 + gul, pkv);
  }
}

// ---------------- decoder persistent kernel ----------------
__global__ __launch_bounds__(1024, 4) void ed_dec_v6(
    const int* __restrict__ src,
    const bf16* __restrict__ KRh, const bf16* __restrict__ KRl, const float* __restrict__ dec_b,
    const bf16* __restrict__ WcTh, const bf16* __restrict__ WcTl, const float* __restrict__ b_cp,
    const bf16* __restrict__ WoTh, const float* __restrict__ b_op,
    const float* __restrict__ Wout_f32, const float* __restrict__ dec_emb,
    const float* __restrict__ hsf, const bf16* __restrict__ hsW,
    unsigned* hpkA, unsigned* hpkB, float* __restrict__ cbuf,
    float* __restrict__ pctx, float* __restrict__ psum, unsigned* ahpk,
    float* __restrict__ rowsum, float* __restrict__ rmax, int* __restrict__ ridx,
    float* __restrict__ out, unsigned* barsG, unsigned* barsL) {
  extern __shared__ char sm[];
  int bid = blockIdx.x, tid = threadIdx.x;
  int bg = bid >> 6, cgl = bid & 63, lid = bid & 63;
  unsigned* barL = barsL + bg * 128;
  int wv = tid >> 6, l = tid & 63, lr = l & 15, lq = l >> 4;
  float c_ = 0.f;
  if (tid < 256) c_ = cbuf[(size_t)(bg * 16 + (tid >> 4)) * 1024 + cgl * 16 + (tid & 15)];
  unsigned *hc = hpkA, *hn = hpkB;
  unsigned lgenL = 0, lgenG = 0;

  if (tid < 16) ((int*)(sm + D_YL))[tid] = 1;
  __syncthreads();
  dec_lstm6(bg, cgl, tid, sm, hc, hn, dec_emb, KRh, KRl, dec_b, c_);
  bar64(barL, lgenL, lid); lgenL++;
  { unsigned* tp = hc; hc = hn; hn = tp; }

  for (int st = 0; st < 32; st++) {
    // ---- P1: attention scores + exp + partial ctx; block = (b, kg) ----
    {
      int b_ = bid >> 2, kg = bid & 3;
      float* hbf = (float*)(sm + D_HBF);
      hbf[tid] = us2f((unsigned short)(ald(hc + (size_t)b_ * 1024 + tid) >> 16));
      __syncthreads();
      float* psc = (float*)(sm + D_PSC);
      {
        int kl = tid >> 4, q = tid & 15;
        const bf16* wrow = hsW + ((size_t)(kg * 64 + kl) * 64 + b_) * 1024 + q * 64;
        float p = 0.f;
#pragma unroll
        for (int j = 0; j < 8; j++) {
          uint4 wv_ = *(const uint4*)(wrow + j * 8);
          int kb = q * 64 + j * 8;
          p += hbf[kb + 0] * us2f(wv_.x & 0xffff) + hbf[kb + 1] * us2f(wv_.x >> 16);
          p += hbf[kb + 2] * us2f(wv_.y & 0xffff) + hbf[kb + 3] * us2f(wv_.y >> 16);
          p += hbf[kb + 4] * us2f(wv_.z & 0xffff) + hbf[kb + 5] * us2f(wv_.z >> 16);
          p += hbf[kb + 6] * us2f(wv_.w & 0xffff) + hbf[kb + 7] * us2f(wv_.w >> 16);
        }
        psc[kl * 17 + q] = p;
      }
      __syncthreads();
      float* ek = (float*)(sm + D_EK);
      if (tid < 64) {
        float sc = 0.f;
#pragma unroll
        for (int q = 0; q < 16; q++) sc += psc[tid * 17 + q];
        ek[tid] = (src[b_ * 256 + kg * 64 + tid] > 0) ? expf(sc) : 0.f;
      }
      __syncthreads();
      float* pc4 = (float*)(sm + D_PC4);
      {
        int cq = tid & 255, kc = tid >> 8;
        float a0 = 0.f, a1 = 0.f, a2 = 0.f, a3 = 0.f;
#pragma unroll 4
        for (int j = 0; j < 16; j++) {
          float e = ek[kc * 16 + j];
          const float* hr = hsf + ((size_t)(kg * 64 + kc * 16 + j) * 64 + b_) * 1024 + cq * 4;
          float4 uv = *(const float4*)hr;
          a0 += e * uv.x; a1 += e * uv.y; a2 += e * uv.z; a3 += e * uv.w;
        }
        pc4[kc * 1024 + cq * 4 + 0] = a0;
        pc4[kc * 1024 + cq * 4 + 1] = a1;
        pc4[kc * 1024 + cq * 4 + 2] = a2;
        pc4[kc * 1024 + cq * 4 + 3] = a3;
      }
      __syncthreads();
      {
        float v = pc4[tid] + pc4[1024 + tid] + pc4[2048 + tid] + pc4[3072 + tid];
        astf(pctx + ((size_t)kg * 64 + b_) * 1024 + tid, v);
      }
      if (tid == 0) {
        float* ek2 = (float*)(sm + D_EK);
        float s_ = 0.f;
        for (int i2 = 0; i2 < 64; i2++) s_ += ek2[i2];
        astf(psum + kg * 64 + b_, s_);
      }
    }
    bar64(barL, lgenL, lid); lgenL++;
    // ---- P3: ctx-reduce + ah = tanh([ctx,h]@W_c + b_c); block = (bg, 16-col) ----
    {
      float* inv_l = (float*)(sm + D_INV);
      if (tid < 16) {
        int rb = bg * 16 + tid;
        float sg = aldf(psum + rb) + aldf(psum + 64 + rb) +
                   aldf(psum + 128 + rb) + aldf(psum + 192 + rb);
        inv_l[tid] = 1.0f / sg;
      }
      __syncthreads();
      float* zs3 = (float*)(sm + D_ZS3);
      {
        int kq = wv;
        f32x4 acc = {0.f, 0.f, 0.f, 0.f};
        const bf16* bh = WcTh + (size_t)(cgl * 16 + lr) * 2048;
        const bf16* bl = WcTl + (size_t)(cgl * 16 + lr) * 2048;
        float inv = inv_l[lr];
#pragma unroll
        for (int i = 0; i < 4; i++) {
          int k = kq * 128 + i * 32 + lq * 8;
          bf8v a_h, a_l;
          if (k < 1024) {
            const float* p0 = pctx + (size_t)(bg * 16 + lr) * 1024 + k;
#pragma unroll
            for (int e = 0; e < 8; e++) {
              float v = (aldf(p0 + e) + aldf(p0 + 65536 + e) +
                         aldf(p0 + 131072 + e) + aldf(p0 + 196608 + e)) * inv;
              unsigned short uh = f2bu(v);
              a_h[e] = (short)uh;
              a_l[e] = (short)f2bu(v - us2f(uh));
            }
          } else {
            const unsigned* hp = hc + (size_t)(bg * 16 + lr) * 1024 + (k - 1024);
#pragma unroll
            for (int e = 0; e < 8; e++) {
              unsigned u = ald(hp + e);
              a_h[e] = (short)(u >> 16);
              a_l[e] = (short)(u & 0xffffu);
            }
          }
          bf8v b_h = *(const bf8v*)(bh + k);
          bf8v b_l = *(const bf8v*)(bl + k);
          acc = MFMA16(a_h, b_h, acc); acc = MFMA16(a_h, b_l, acc);
          acc = MFMA16(a_l, b_h, acc); acc = MFMA16(a_l, b_l, acc);
        }
#pragma unroll
        for (int r = 0; r < 4; r++) zs3[(kq * 16 + lq * 4 + r) * 17 + lr] = acc[r];
      }
      __syncthreads();
      if (tid < 256) {
        int grow = tid >> 4, gcol = tid & 15;
        float v = 0.f;
#pragma unroll
        for (int q = 0; q < 16; q++) v += zs3[(q * 16 + grow) * 17 + gcol];
        v += b_cp[cgl * 16 + gcol];
        float ahv = tanhf(v);
        unsigned short uh = f2bu(ahv);
        unsigned pkv = ((unsigned)uh << 16) | (unsigned)f2bu(ahv - us2f(uh));
        ast(ahpk + (size_t)(bg * 16 + grow) * 1024 + cgl * 16 + gcol, pkv);
      }
    }
    gridbar2(barsG, lgenG); lgenG++;
    // ---- P4: chunked hi-only logits (gload16 W staging) + exp-sum / top-2 ----
    {
      int base = bid * 125;
      bf16* abuf = (bf16*)(sm + D4_A);
      bf16* wbuf = (bf16*)(sm + D4_W);
      int rg = wv >> 2, cpair = wv & 3;
      f32x4 acc0 = {0.f, 0.f, 0.f, 0.f}, acc1 = {0.f, 0.f, 0.f, 0.f};
      for (int kc = 0; kc < 8; kc++) {
        int k0 = kc * 128;
        __syncthreads();
        {
          int row = tid >> 4, l16 = tid & 15;
          const unsigned* ap = ahpk + (size_t)row * 1024 + k0 + l16 * 8;
          unsigned u0 = ald(ap), u1 = ald(ap + 1), u2 = ald(ap + 2), u3 = ald(ap + 3);
          unsigned u4 = ald(ap + 4), u5 = ald(ap + 5), u6 = ald(ap + 6), u7 = ald(ap + 7);
          uint4 hv;
          hv.x = (u0 >> 16) | (u1 & 0xffff0000u);
          hv.y = (u2 >> 16) | (u3 & 0xffff0000u);
          hv.z = (u4 >> 16) | (u5 & 0xffff0000u);
          hv.w = (u6 >> 16) | (u7 & 0xffff0000u);
          *(uint4*)((char*)abuf + row * 256 + ((l16 * 16) ^ ((row & 7) << 4))) = hv;
        }
#pragma unroll
        for (int r = 0; r < 2; r++) {
          int i = wv * 128 + r * 64 + l;
          int col = i >> 4, j = i & 15;
          int ccol = col < 125 ? col : 124;
          size_t se = (size_t)(base + ccol) * 1024 + k0 + ((size_t)(j ^ (col & 7)) << 3);
          gload16(WoTh + se, (char*)wbuf + wv * 2048 + r * 1024);
        }
        __syncthreads();
#pragma unroll
        for (int s = 0; s < 4; s++) {
          int kl = s * 32 + lq * 8;
          int ar = rg * 16 + lr;
          bf8v a = *(const bf8v*)((char*)abuf + ar * 256 + ((kl * 2) ^ ((ar & 7) << 4)));
          int c0 = cpair * 32 + lr, c1 = c0 + 16;
          bf8v b0 = *(const bf8v*)((char*)wbuf + c0 * 256 + ((kl * 2) ^ ((c0 & 7) << 4)));
          bf8v b1 = *(const bf8v*)((char*)wbuf + c1 * 256 + ((kl * 2) ^ ((c1 & 7) << 4)));
          acc0 = MFMA16(a, b0, acc0);
          acc1 = MFMA16(a, b1, acc1);
        }
      }
      __syncthreads();
      float* e = (float*)(sm + D4_E);
      {
        int cl0 = cpair * 32 + lr;
        if (cl0 < 125) {
#pragma unroll
          for (int r = 0; r < 4; r++)
            e[(rg * 16 + lq * 4 + r) * 129 + cl0] = acc0[r] + b_op[base + cl0];
        }
        int cl1 = cpair * 32 + 16 + lr;
        if (cl1 < 125) {
#pragma unroll
          for (int r = 0; r < 4; r++)
            e[(rg * 16 + lq * 4 + r) * 129 + cl1] = acc1[r] + b_op[base + cl1];
        }
      }
      __syncthreads();
      if (tid < 64) {
        float sm_ = 0.f, v1 = -1e30f, v2 = -1e30f;
        int i1 = 0, i2 = 0;
        for (int c2 = 0; c2 < 125; c2++) {
          float v = e[tid * 129 + c2];
          sm_ += expf(v);
          if (v > v1) { v2 = v1; i2 = i1; v1 = v; i1 = base + c2; }
          else if (v > v2) { v2 = v; i2 = base + c2; }
        }
        astf(rowsum + bid * 64 + tid, sm_);
        astf(rmax + (bid * 64 + tid) * 2 + 0, v1);
        ast((unsigned*)ridx + (bid * 64 + tid) * 2 + 0, (unsigned)i1);
        astf(rmax + (bid * 64 + tid) * 2 + 1, v2);
        ast((unsigned*)ridx + (bid * 64 + tid) * 2 + 1, (unsigned)i2);
      }
    }
    gridbar2(barsG, lgenG); lgenG++;
    // ---- P5: probs write (NT) + candidate refine (f64, NT) + next LSTM ----
    {
      float* psc2 = (float*)(sm + D_PSC2);
      {
        int rr = tid & 63, pp = tid >> 6;
        float s_ = 0.f;
#pragma unroll 4
        for (int cu = pp * 16; cu < pp * 16 + 16; cu++) s_ += aldf(rowsum + cu * 64 + rr);
        psc2[rr * 17 + pp] = s_;
      }
      __syncthreads();
      float* rt = (float*)(sm + D_RT);
      if (tid < 64) {
        float s_ = 0.f;
#pragma unroll
        for (int p2 = 0; p2 < 16; p2++) s_ += psc2[tid * 17 + p2];
        rt[tid] = s_;
      }
      __syncthreads();
      float* e = (float*)(sm + D4_E);
      {
        int base = bid * 125;
        for (int i = tid; i < 8000; i += 1024) {
          int r_ = i / 125, c2 = i - r_ * 125;
          float pv = expf(e[r_ * 129 + c2]) / rt[r_];
          __builtin_nontemporal_store(pv, out + ((size_t)r_ * 32 + st) * 32000 + base + c2);
        }
      }
      if (st < 31) {
        float* gmx = (float*)(sm + D_GMX);
        int* ccnt = (int*)(sm + D_CCN);
        int* cand = (int*)(sm + D_CAND);
        int* y_l = (int*)(sm + D_YL);
        int r16 = tid & 15, ch = tid >> 4;
        int rowg = bg * 16 + r16;
        float vloc[8]; int iloc[8];
        {
          float m_ = -1e30f;
#pragma unroll
          for (int ee = 0; ee < 8; ee++) {
            int ent = ch * 8 + ee;
            vloc[ee] = aldf(rmax + ((size_t)(ent >> 1) * 64 + rowg) * 2 + (ent & 1));
            iloc[ee] = (int)ald((const unsigned*)ridx + ((size_t)(ent >> 1) * 64 + rowg) * 2 + (ent & 1));
            m_ = fmaxf(m_, vloc[ee]);
          }
          gmx[r16 * 65 + ch] = m_;
        }
        if (tid < 16) ccnt[tid] = 0;
        __syncthreads();
        if (tid < 16) {
          float g_ = -1e30f;
#pragma unroll
          for (int j = 0; j < 64; j++) g_ = fmaxf(g_, gmx[tid * 65 + j]);
          gmx[tid * 65 + 64] = g_;
        }
        __syncthreads();
        {
          float thr = gmx[r16 * 65 + 64] - DELTA;
#pragma unroll
          for (int ee = 0; ee < 8; ee++) {
            if (vloc[ee] >= thr) {
              int slot = atomicAdd(&ccnt[r16], 1);
              if (slot < 8) cand[r16 * 8 + slot] = iloc[ee];
            }
          }
        }
        __syncthreads();
        {
          int row2 = wv;
          int rowg2 = bg * 16 + row2;
          int cnt = ccnt[row2]; if (cnt > 8) cnt = 8;
          double bv = -1e30; int bi_ = 0x7fffffff;
          for (int ci = 0; ci < cnt; ci++) {
            int c = cand[row2 * 8 + ci];
            double s_ = 0.0;
            for (int k = l; k < 1024; k += 64) {
              unsigned u = ald(ahpk + (size_t)rowg2 * 1024 + k);
              float av = us2f((unsigned short)(u >> 16)) + us2f((unsigned short)(u & 0xffffu));
              float wv_ = __builtin_nontemporal_load(Wout_f32 + (size_t)k * 32000 + c);
              s_ += (double)av * (double)wv_;
            }
#pragma unroll
            for (int off = 32; off > 0; off >>= 1) s_ += __shfl_down(s_, off);
            if (l == 0) {
              s_ += (double)b_op[c];
              if (s_ > bv || (s_ == bv && c < bi_)) { bv = s_; bi_ = c; }
            }
          }
          if (l == 0) y_l[row2] = bi_;
        }
        __syncthreads();
        dec_lstm6(bg, cgl, tid, sm, hc, hn, dec_emb, KRh, KRl, dec_b, c_);
      }
    }
    bar64(barL, lgenL, lid); lgenL++;
    { unsigned* tp = hc; hc = hn; hn = tp; }
  }
}

// ---------------- host launch ----------------
extern "C" void kernel_launch(void* const* d_in, const int* in_sizes, int n_in,
                              void* d_out, int out_size, void* d_ws, size_t ws_size,
                              hipStream_t stream) {
  (void)in_sizes; (void)n_in; (void)out_size; (void)ws_size;
  const int*   src     = (const int*)  d_in[0];
  const float* enc_emb = (const float*)d_in[1];
  const float* enc_K   = (const float*)d_in[2];
  const float* enc_R   = (const float*)d_in[3];
  const float* enc_b   = (const float*)d_in[4];
  const float* dec_emb = (const float*)d_in[5];
  const float* dec_K   = (const float*)d_in[6];
  const float* dec_R   = (const float*)d_in[7];
  const float* dec_b   = (const float*)d_in[8];
  const float* W_a     = (const float*)d_in[9];
  const float* W_c     = (const float*)d_in[10];
  const float* b_c     = (const float*)d_in[11];
  const float* W_out   = (const float*)d_in[12];
  const float* b_out   = (const float*)d_in[13];
  char* ws = (char*)d_ws;

  hipFuncSetAttribute((const void*)ed_enc_v6, hipFuncAttributeMaxDynamicSharedMemorySize, 163840);
  hipFuncSetAttribute((const void*)ed_dec_v6, hipFuncAttributeMaxDynamicSharedMemorySize, 163840);

  bf16* KpTh = (bf16*)(ws + OKPT_H);
  bf16* KpTl = (bf16*)(ws + OKPT_L);
  bf16* RpTh = (bf16*)(ws + ORPT_H);
  bf16* RpTl = (bf16*)(ws + ORPT_L);
  bf16* WaT  = (bf16*)(ws + OWAT);
  bf16* xeh  = (bf16*)(ws + OXE_H);
  bf16* xel  = (bf16*)(ws + OXE_L);
  float* hsf = (float*)(ws + OHSF5);
  bf16* hsb  = (bf16*)(ws + OHSB5);
  unsigned* hpkE0 = (unsigned*)(ws + OHPK_E0);
  unsigned* hpkE1 = (unsigned*)(ws + OHPK_E1);
  unsigned* hpkD0 = (unsigned*)(ws + OHPK_D0);
  float* cbuf = (float*)(ws + OCBUF5);
  unsigned* ahpk = (unsigned*)(ws + OAHPK);
  float* rsum = (float*)(ws + ORSUM5);
  float* rmaxp = (float*)(ws + ORMAX5);
  int*  ridxp = (int*)(ws + ORIDX5);
  float* psum = (float*)(ws + OPSUM5);
  unsigned* barsE = (unsigned*)(ws + OBARS5);
  unsigned* barsG = (unsigned*)(ws + OBARS5 + 4096);
  unsigned* barsL = (unsigned*)(ws + OBARS5 + 8192);
  bf16* XkL  = (bf16*)(ws + OXK_L5);
  bf16* XkH  = (bf16*)d_out;
  bf16* WcTh = (bf16*)(ws + OWCT_H);
  bf16* WcTl = (bf16*)(ws + OWCT_L);
  float* pctx = (float*)(ws + OPCTX5);
  bf16* WoTh = (bf16*)(ws + OWOT5);
  bf16* KRTh = (bf16*)(ws + OKRTH5);
  bf16* KRTl = (bf16*)(ws + OKRTL5);
  bf16* hsW  = (bf16*)(ws + OHSW5);

  ed_zero_v6<<<512, 256, 0, stream>>>((float4*)(ws + XCH), 131072);
  ed_transpose_split_v6<<<dim3(128, 32), 256, 0, stream>>>(enc_K, KpTh, KpTl, 1024, 4096, 1024, 0, 1);
  ed_transpose_split_v6<<<dim3(128, 32), 256, 0, stream>>>(enc_R, RpTh, RpTl, 1024, 4096, 1024, 0, 1);
  ed_transpose_v6<<<dim3(32, 32), 256, 0, stream>>>(W_a, WaT, 1024, 1024, 1024, 0, 0);
  ed_gather_split_v6<<<16384, 256, 0, stream>>>(src, enc_emb, xeh, xel);
  ed_gemm3_v6<<<dim3(32, 128), 256, 0, stream>>>(xeh, xel, KpTh, KpTl, XkH, XkL, 16384, 4096, 1024);
  ed_transpose_split_v6<<<dim3(32, 64), 256, 0, stream>>>(W_c, WcTh, WcTl, 2048, 1024, 2048, 0, 0);
  ed_enc_v6<<<256, 1024, 87040, stream>>>(src, RpTh, RpTl, XkH, XkL, enc_b,
                                          hpkE0, hpkE1, cbuf, hsf, hsb, barsE);
  ed_transpose_v6<<<dim3(1000, 32), 256, 0, stream>>>(W_out, WoTh, 1024, 32000, 1024, 0, 0);
  ed_transpose_split_v6<<<dim3(128, 32), 256, 0, stream>>>(dec_K, KRTh, KRTl, 1024, 4096, 2048, 0, 1);
  ed_transpose_split_v6<<<dim3(128, 32), 256, 0, stream>>>(dec_R, KRTh, KRTl, 1024, 4096, 2048, 1024, 1);
  ed_gemm_bt_v6<<<dim3(8, 128), 256, 0, stream>>>(hsb, WaT, hsW, 16384, 1024, 1024);
  ed_dec_v6<<<256, 1024, 150528, stream>>>(src, KRTh, KRTl, dec_b, WcTh, WcTl, b_c,
                                           WoTh, b_out, W_out, dec_emb, hsf, hsW,
                                           hpkE0, hpkD0, cbuf, pctx, psum, ahpk,
                                           rsum, rmaxp, ridxp, (float*)d_out, barsG, barsL);
}